// Round 6
// baseline (1237.012 us; speedup 1.0000x reference)
//
#include <hip/hip_runtime.h>
#include <hip/hip_bf16.h>

// Problem constants (fixed by the reference)
#define NN 8192   // nodes per side
#define ED 128    // embedding dim E
#define DD 64     // attention dim D
#define KK 32     // neighbors per node
#define MM 4      // metapaths

// -------------------------------------------------------------------------
// proj_kernel: outP[m, row, d] = sum_e emb[row,e] * W[m,e,d] (+ Bias[m,d])
// One thread per output element. No LDS, no sync — correct by construction.
// -------------------------------------------------------------------------
__global__ void proj_kernel(const float* __restrict__ emb,   // [NN,ED] f32
                            const float* __restrict__ W,     // [MM,ED,DD]
                            const float* __restrict__ Bias,  // [MM,DD] or nullptr
                            float* __restrict__ outP)        // [MM,NN,DD]
{
    const int gid = blockIdx.x * blockDim.x + threadIdx.x;   // ((m*NN)+row)*DD+d
    if (gid >= MM * NN * DD) return;
    const int d   = gid & (DD - 1);
    const int row = (gid >> 6) & (NN - 1);
    const int m   = gid >> 19;

    const float* er = emb + (size_t)row * ED;
    const float* Wm = W + (size_t)m * ED * DD + d;
    float acc = Bias ? Bias[m * DD + d] : 0.0f;
    for (int e = 0; e < ED; ++e)
        acc = fmaf(er[e], Wm[(size_t)e * DD], acc);
    outP[gid] = acc;
}

// -------------------------------------------------------------------------
// attn_kernel: one wave (64 threads) per (m, node j). All reductions are
// either per-thread serial loops or a serial loop on thread 0 via LDS.
// grid: (NN, MM), block: 64
// -------------------------------------------------------------------------
__global__ void attn_kernel(const float* __restrict__ src,    // [NN,ED]
                            const float* __restrict__ other,  // [NN,ED]
                            const int*   __restrict__ nbrs,   // [MM,NN,KK]
                            const float* __restrict__ S,      // [MM,NN,DD]
                            const float* __restrict__ Pn,     // [MM,NN,DD]
                            const float* __restrict__ Xv,     // [MM,DD]
                            const float* __restrict__ Wq,     // [MM,ED,DD]
                            const float* __restrict__ Bq,     // [MM,DD]
                            const float* __restrict__ Qv,     // [MM,DD]
                            float* __restrict__ Hout,         // [MM,NN,ED]
                            float* __restrict__ beta_acc)     // [MM]
{
    const int j = blockIdx.x;
    const int m = blockIdx.y;
    const int t = threadIdx.x;   // 0..63

    __shared__ float S_sh[DD];
    __shared__ float X_sh[DD];
    __shared__ float sc_sh[KK];
    __shared__ float A_sh[KK];
    __shared__ float H_sh[ED];
    __shared__ float red_sh[DD];
    __shared__ int   idx_sh[KK];

    S_sh[t] = S[((size_t)m * NN + j) * DD + t];
    X_sh[t] = Xv[m * DD + t];
    if (t < KK) idx_sh[t] = nbrs[((size_t)m * NN + j) * KK + t];
    __syncthreads();

    // ---- scores: lane t handles neighbor t, serial over d
    if (t < KK) {
        const float* pr = Pn + ((size_t)m * NN + idx_sh[t]) * DD;
        float s = 0.0f;
        for (int d = 0; d < DD; ++d)
            s += tanhf(S_sh[d] + pr[d]) * X_sh[d];
        sc_sh[t] = s;
    }
    __syncthreads();

    // ---- softmax (full-axis baseline semantics), serial on thread 0
    if (t == 0) {
        const float baseline = (m == 0) ? -1e-9f : (1.0f / (float)NN);
        float mx = baseline;
        for (int i = 0; i < KK; ++i) mx = fmaxf(mx, sc_sh[i]);
        float sum = 0.0f;
        for (int i = 0; i < KK; ++i) {
            const float e = expf(sc_sh[i] - mx);
            A_sh[i] = e;
            sum += e;
        }
        const float denom = sum + (float)(NN - KK) * expf(baseline - mx);
        for (int i = 0; i < KK; ++i) A_sh[i] /= denom;
    }
    __syncthreads();

    // ---- H aggregation: thread t handles e = t and e = t+64
    for (int e = t; e < ED; e += 64) {
        float acc = src[(size_t)j * ED + e];
        for (int k = 0; k < KK; ++k)
            acc = fmaf(A_sh[k], other[(size_t)idx_sh[k] * ED + e], acc);
        H_sh[e] = acc;
        Hout[((size_t)m * NN + j) * ED + e] = acc;
    }
    __syncthreads();

    // ---- sem: thread t = output dim d, serial over e; reduce on thread 0
    {
        const float* Wqm = Wq + (size_t)m * ED * DD;
        float acc = Bq[m * DD + t];
        for (int e = 0; e < ED; ++e)
            acc = fmaf(H_sh[e], Wqm[(size_t)e * DD + t], acc);
        red_sh[t] = tanhf(acc) * Qv[m * DD + t];
    }
    __syncthreads();
    if (t == 0) {
        float s = 0.0f;
        for (int d = 0; d < DD; ++d) s += red_sh[d];
        atomicAdd(&beta_acc[m], s);
    }
}

// -------------------------------------------------------------------------
// combine: beta = softmax(beta_acc / NN); out = sum_m beta[m] * H[m]
// Output is FLOAT32 (the reference returns float32; harness reads f32).
// -------------------------------------------------------------------------
__global__ void combine_kernel(const float* __restrict__ Hin,      // [MM,NN,ED]
                               const float* __restrict__ beta_acc, // [MM]
                               float* __restrict__ outp)           // [NN,ED] f32
{
    const int i = blockIdx.x * blockDim.x + threadIdx.x;
    if (i >= NN * ED) return;
    const float b0 = beta_acc[0] * (1.0f / NN);
    const float b1 = beta_acc[1] * (1.0f / NN);
    const float b2 = beta_acc[2] * (1.0f / NN);
    const float b3 = beta_acc[3] * (1.0f / NN);
    const float mx = fmaxf(fmaxf(b0, b1), fmaxf(b2, b3));
    const float e0 = expf(b0 - mx), e1 = expf(b1 - mx);
    const float e2 = expf(b2 - mx), e3 = expf(b3 - mx);
    const float inv = 1.0f / (e0 + e1 + e2 + e3);
    const size_t st = (size_t)NN * ED;
    outp[i] = (e0 * Hin[i] + e1 * Hin[st + i] + e2 * Hin[2 * st + i]
               + e3 * Hin[3 * st + i]) * inv;
}

__global__ void zero_beta(float* p)
{
    if (threadIdx.x < MM) p[threadIdx.x] = 0.0f;
}

// -------------------------------------------------------------------------
extern "C" void kernel_launch(void* const* d_in, const int* in_sizes, int n_in,
                              void* d_out, int out_size, void* d_ws, size_t ws_size,
                              hipStream_t stream)
{
    // dict order: user, product, V, X, W_p, B_p, W_q, B_q, Q, user_nbrs, product_nbrs
    const float* user    = (const float*)d_in[0];   // [NN,ED]
    const float* product = (const float*)d_in[1];   // [NN,ED]
    const float* V   = (const float*)d_in[2];       // [2,MM,ED,DD]
    const float* X   = (const float*)d_in[3];       // [2,MM,1,DD]
    const float* W_p = (const float*)d_in[4];       // [2,MM,ED,DD]
    const float* B_p = (const float*)d_in[5];       // [2,MM,DD]
    const float* W_q = (const float*)d_in[6];       // [2,MM,ED,DD]
    const float* B_q = (const float*)d_in[7];       // [2,MM,DD]
    const float* Q   = (const float*)d_in[8];       // [2,MM,1,DD]
    const int* user_nbrs    = (const int*)d_in[9];  // [MM,NN,KK]
    const int* product_nbrs = (const int*)d_in[10]; // [MM,NN,KK]

    float* out  = (float*)d_out;                    // [2,NN,ED] f32
    float* out0 = out;                              // user_out (also phase-1 input)
    float* out1 = out + (size_t)NN * ED;            // product_out

    // workspace layout (f32)
    float* ws   = (float*)d_ws;
    float* beta = ws;                                   // 64 (padded)
    float* S    = beta + 64;                            // MM*NN*DD
    float* Pn   = S    + (size_t)MM * NN * DD;          // MM*NN*DD
    float* H    = Pn   + (size_t)MM * NN * DD;          // MM*NN*ED

    const size_t MED = (size_t)MM * ED * DD;            // per-phase weight slice
    const size_t MD  = (size_t)MM * DD;

    const int pThreads = 256;
    const int pBlocks  = (MM * NN * DD + pThreads - 1) / pThreads;
    const dim3 gA(NN, MM);
    const int cThreads = 256;
    const int cBlocks  = (NN * ED + cThreads - 1) / cThreads;

    // ===================== phase 0: user side =====================
    {
        zero_beta<<<1, 64, 0, stream>>>(beta);
        proj_kernel<<<pBlocks, pThreads, 0, stream>>>(user, V, B_p, S);
        proj_kernel<<<pBlocks, pThreads, 0, stream>>>(product, W_p, nullptr, Pn);
        attn_kernel<<<gA, 64, 0, stream>>>(user, product, user_nbrs,
                                           S, Pn, X, W_q, B_q, Q, H, beta);
        combine_kernel<<<cBlocks, cThreads, 0, stream>>>(H, beta, out0);
    }

    // ===================== phase 1: product side ==================
    // attends over the UPDATED user embeddings (= out0, f32)
    {
        zero_beta<<<1, 64, 0, stream>>>(beta);
        proj_kernel<<<pBlocks, pThreads, 0, stream>>>(product, V + MED, B_p + MD, S);
        proj_kernel<<<pBlocks, pThreads, 0, stream>>>(out0, W_p + MED, nullptr, Pn);
        attn_kernel<<<gA, 64, 0, stream>>>(product, out0, product_nbrs,
                                           S, Pn, X + MD, W_q + MED, B_q + MD,
                                           Q + MD, H, beta);
        combine_kernel<<<cBlocks, cThreads, 0, stream>>>(H, beta, out1);
    }
}

// Round 7
// 459.179 us; speedup vs baseline: 2.6940x; 2.6940x over previous
//
#include <hip/hip_runtime.h>
#include <hip/hip_bf16.h>

// Problem constants (fixed by the reference)
#define NN 8192   // nodes per side
#define ED 128    // embedding dim E
#define DD 64     // attention dim D
#define KK 32     // neighbors per node
#define MM 4      // metapaths

// -------------------------------------------------------------------------
// proj_kernel: tiled GEMM  outP[m,row,d] = sum_e emb[row,e]*W[m,e,d] (+Bias)
// Block: 256 threads -> 128-row x 64-col tile, 8x4 micro-tile per thread.
// K split in two 64-halves staged through LDS. grid: (NN/128, MM)
// -------------------------------------------------------------------------
__global__ __launch_bounds__(256) void proj_kernel(
    const float* __restrict__ emb,   // [NN,ED]
    const float* __restrict__ W,     // [MM,ED,DD]
    const float* __restrict__ Bias,  // [MM,DD] or nullptr
    float* __restrict__ outP)        // [MM,NN,DD]
{
    const int m   = blockIdx.y;
    const int r0  = blockIdx.x * 128;
    const int tid = threadIdx.x;

    __shared__ float A_sh[128][65];   // pad 65: conflict-free column reads
    __shared__ float W_sh[64][64];

    const int tc = tid & 15;          // col group -> d0 = 4*tc
    const int tr = tid >> 4;          // row group -> rows 8*tr..8*tr+7
    const int d0 = tc * 4;
    const int rb = tr * 8;

    float acc[8][4];
    #pragma unroll
    for (int i = 0; i < 8; ++i)
        #pragma unroll
        for (int c = 0; c < 4; ++c) acc[i][c] = 0.0f;

    for (int kb = 0; kb < 2; ++kb) {
        if (kb) __syncthreads();
        // stage A half-tile: rows r0..r0+127, cols kb*64..kb*64+63
        {
            const float4* g = (const float4*)emb;
            #pragma unroll
            for (int it = 0; it < 8; ++it) {
                const int idx = tid + it * 256;  // 0..2047
                const int r   = idx >> 4;
                const int c4  = idx & 15;
                const float4 v = g[(size_t)(r0 + r) * (ED / 4) + kb * 16 + c4];
                float* dst = &A_sh[r][c4 * 4];
                dst[0] = v.x; dst[1] = v.y; dst[2] = v.z; dst[3] = v.w;
            }
        }
        // stage W half: rows kb*64..kb*64+63 (e), cols 0..63 (d)
        {
            const float4* g = (const float4*)(W + ((size_t)m * ED + kb * 64) * DD);
            float4* d4 = (float4*)&W_sh[0][0];
            #pragma unroll
            for (int it = 0; it < 4; ++it)
                d4[tid + it * 256] = g[tid + it * 256];
        }
        __syncthreads();

        #pragma unroll 2
        for (int e = 0; e < 64; ++e) {
            const float4 wv = *(const float4*)&W_sh[e][d0];
            #pragma unroll
            for (int i = 0; i < 8; ++i) {
                const float a = A_sh[rb + i][e];
                acc[i][0] = fmaf(a, wv.x, acc[i][0]);
                acc[i][1] = fmaf(a, wv.y, acc[i][1]);
                acc[i][2] = fmaf(a, wv.z, acc[i][2]);
                acc[i][3] = fmaf(a, wv.w, acc[i][3]);
            }
        }
    }

    float4 bv = make_float4(0.0f, 0.0f, 0.0f, 0.0f);
    if (Bias) bv = *(const float4*)&Bias[m * DD + d0];
    #pragma unroll
    for (int i = 0; i < 8; ++i) {
        const int row = r0 + rb + i;
        float4 o;
        o.x = acc[i][0] + bv.x; o.y = acc[i][1] + bv.y;
        o.z = acc[i][2] + bv.z; o.w = acc[i][3] + bv.w;
        *(float4*)&outP[((size_t)m * NN + row) * DD + d0] = o;
    }
}

// -------------------------------------------------------------------------
// attn_kernel: 4 waves/block, one (m, j) per wave. Lanes = d (coalesced Pn
// rows), register softmax via shuffles, float2 H aggregation, Wq in LDS,
// slotted beta atomics. grid: (NN/4, MM), block 256.
// -------------------------------------------------------------------------
__global__ __launch_bounds__(256) void attn_kernel(
    const float* __restrict__ src,    // [NN,ED]
    const float* __restrict__ other,  // [NN,ED]
    const int*   __restrict__ nbrs,   // [MM,NN,KK]
    const float* __restrict__ S,      // [MM,NN,DD]
    const float* __restrict__ Pn,     // [MM,NN,DD]
    const float* __restrict__ Xv,     // [MM,DD]
    const float* __restrict__ Wq,     // [MM,ED,DD]
    const float* __restrict__ Bq,     // [MM,DD]
    const float* __restrict__ Qv,     // [MM,DD]
    float* __restrict__ Hout,         // [MM,NN,ED]
    float* __restrict__ beta_part)    // [256,MM]
{
    const int m    = blockIdx.y;
    const int tid  = threadIdx.x;
    const int w    = tid >> 6;
    const int lane = tid & 63;
    const int j    = blockIdx.x * 4 + w;

    __shared__ float Wq_sh[ED][DD];   // 32 KB, shared by the 4 waves (same m)
    __shared__ float H_sh[4][ED];     // per-wave H row
    __shared__ int   idx_sh[4][KK];   // per-wave neighbor ids

    // cooperative stage of Wq[m]
    {
        const float4* g  = (const float4*)(Wq + (size_t)m * ED * DD);
        float4* d4 = (float4*)&Wq_sh[0][0];
        #pragma unroll
        for (int i = 0; i < 8; ++i)
            d4[tid + i * 256] = g[tid + i * 256];
    }
    if (lane < KK)
        idx_sh[w][lane] = nbrs[((size_t)m * NN + j) * KK + lane];
    const float Sreg = S[((size_t)m * NN + j) * DD + lane];
    const float Xreg = Xv[m * DD + lane];
    __syncthreads();

    // ---- scores: per k, coalesced 256B Pn row, full-wave tanh + butterfly
    float score = -1e30f;
    #pragma unroll 4
    for (int k = 0; k < KK; ++k) {
        const int jk = idx_sh[w][k];
        float p = tanhf(Sreg + Pn[((size_t)m * NN + jk) * DD + lane]) * Xreg;
        #pragma unroll
        for (int off = 32; off; off >>= 1) p += __shfl_xor(p, off, 64);
        if (lane == k) score = p;     // lane k keeps score[k]
    }

    // ---- softmax with full-axis baseline (all in registers)
    const float baseline = (m == 0) ? -1e-9f : (1.0f / (float)NN);
    float mx = score;
    #pragma unroll
    for (int off = 32; off; off >>= 1) mx = fmaxf(mx, __shfl_xor(mx, off, 64));
    mx = fmaxf(mx, baseline);
    const float ev = (lane < KK) ? expf(score - mx) : 0.0f;
    float sum = ev;
    #pragma unroll
    for (int off = 32; off; off >>= 1) sum += __shfl_xor(sum, off, 64);
    const float denom = sum + (float)(NN - KK) * expf(baseline - mx);
    const float A = ev / denom;       // valid in lanes 0..31

    // ---- H aggregation: lane covers elements {2*lane, 2*lane+1}
    float2 h = ((const float2*)(src + (size_t)j * ED))[lane];
    #pragma unroll 4
    for (int k = 0; k < KK; ++k) {
        const float a  = __shfl(A, k, 64);
        const int   jk = idx_sh[w][k];
        const float2 o = ((const float2*)(other + (size_t)jk * ED))[lane];
        h.x = fmaf(a, o.x, h.x);
        h.y = fmaf(a, o.y, h.y);
    }
    ((float2*)&H_sh[w][0])[lane] = h;
    ((float2*)(Hout + ((size_t)m * NN + j) * ED))[lane] = h;

    // ---- sem matvec + beta partial (4 independent accumulators)
    float a0 = 0.f, a1 = 0.f, a2 = 0.f, a3 = 0.f;
    for (int e = 0; e < ED; e += 4) {
        a0 = fmaf(H_sh[w][e    ], Wq_sh[e    ][lane], a0);
        a1 = fmaf(H_sh[w][e + 1], Wq_sh[e + 1][lane], a1);
        a2 = fmaf(H_sh[w][e + 2], Wq_sh[e + 2][lane], a2);
        a3 = fmaf(H_sh[w][e + 3], Wq_sh[e + 3][lane], a3);
    }
    float sm = tanhf((a0 + a1) + (a2 + a3) + Bq[m * DD + lane]) * Qv[m * DD + lane];
    #pragma unroll
    for (int off = 32; off; off >>= 1) sm += __shfl_xor(sm, off, 64);
    if (lane == 0)
        atomicAdd(&beta_part[((blockIdx.x * 4 + w) & 255) * MM + m], sm);
}

// -------------------------------------------------------------------------
// beta_reduce: fold 256 slots -> beta_raw[m]/NN -> softmax -> bw[4]. 1 wave.
// -------------------------------------------------------------------------
__global__ void beta_reduce(const float* __restrict__ bp, float* __restrict__ bw)
{
    const int lane = threadIdx.x;     // 0..63
    const int m = lane & 3, g = lane >> 2;
    float s = 0.0f;
    for (int i = 0; i < 16; ++i)
        s += bp[(g * 16 + i) * MM + m];
    #pragma unroll
    for (int off = 4; off < 64; off <<= 1) s += __shfl_xor(s, off, 64);
    const float v = s * (1.0f / (float)NN);
    float mx = v;
    mx = fmaxf(mx, __shfl_xor(mx, 1, 64));
    mx = fmaxf(mx, __shfl_xor(mx, 2, 64));
    const float e = expf(v - mx);
    float es = e;
    es += __shfl_xor(es, 1, 64);
    es += __shfl_xor(es, 2, 64);
    if (lane < MM) bw[lane] = e / es;
}

// -------------------------------------------------------------------------
// combine: out = sum_m bw[m] * H[m]   (float4 over 1M elements)
// -------------------------------------------------------------------------
__global__ __launch_bounds__(256) void combine_kernel(
    const float* __restrict__ Hin,    // [MM,NN,ED]
    const float* __restrict__ bw,     // [4] softmaxed
    float* __restrict__ outp)         // [NN,ED]
{
    const int i = blockIdx.x * 256 + threadIdx.x;   // float4 index
    const float b0 = bw[0], b1 = bw[1], b2 = bw[2], b3 = bw[3];
    const size_t st = (size_t)NN * ED / 4;
    const float4* h = (const float4*)Hin;
    const float4 x0 = h[i], x1 = h[st + i], x2 = h[2 * st + i], x3 = h[3 * st + i];
    float4 r;
    r.x = b0 * x0.x + b1 * x1.x + b2 * x2.x + b3 * x3.x;
    r.y = b0 * x0.y + b1 * x1.y + b2 * x2.y + b3 * x3.y;
    r.z = b0 * x0.z + b1 * x1.z + b2 * x2.z + b3 * x3.z;
    r.w = b0 * x0.w + b1 * x1.w + b2 * x2.w + b3 * x3.w;
    ((float4*)outp)[i] = r;
}

__global__ void zero_bp(float* p) { p[threadIdx.x] = 0.0f; }  // <<<1,1024>>>

// -------------------------------------------------------------------------
extern "C" void kernel_launch(void* const* d_in, const int* in_sizes, int n_in,
                              void* d_out, int out_size, void* d_ws, size_t ws_size,
                              hipStream_t stream)
{
    // dict order: user, product, V, X, W_p, B_p, W_q, B_q, Q, user_nbrs, product_nbrs
    const float* user    = (const float*)d_in[0];
    const float* product = (const float*)d_in[1];
    const float* V   = (const float*)d_in[2];
    const float* X   = (const float*)d_in[3];
    const float* W_p = (const float*)d_in[4];
    const float* B_p = (const float*)d_in[5];
    const float* W_q = (const float*)d_in[6];
    const float* B_q = (const float*)d_in[7];
    const float* Q   = (const float*)d_in[8];
    const int* user_nbrs    = (const int*)d_in[9];
    const int* product_nbrs = (const int*)d_in[10];

    float* out  = (float*)d_out;            // [2,NN,ED] f32
    float* out0 = out;                      // user_out (phase-1 input too)
    float* out1 = out + (size_t)NN * ED;    // product_out

    // workspace (f32)
    float* ws = (float*)d_ws;
    float* bp = ws;                               // 256*MM = 1024
    float* bw = bp + 1024;                        // 16 (pad)
    float* S  = bw + 16;                          // MM*NN*DD
    float* Pn = S  + (size_t)MM * NN * DD;        // MM*NN*DD
    float* H  = Pn + (size_t)MM * NN * DD;        // MM*NN*ED

    const size_t MED = (size_t)MM * ED * DD;
    const size_t MD  = (size_t)MM * DD;

    const dim3 gP(NN / 128, MM);
    const dim3 gA(NN / 4, MM);
    const int cBlocks = (NN * ED / 4) / 256;

    // ===================== phase 0: user side =====================
    {
        zero_bp<<<1, 1024, 0, stream>>>(bp);
        proj_kernel<<<gP, 256, 0, stream>>>(user, V, B_p, S);
        proj_kernel<<<gP, 256, 0, stream>>>(product, W_p, nullptr, Pn);
        attn_kernel<<<gA, 256, 0, stream>>>(user, product, user_nbrs,
                                            S, Pn, X, W_q, B_q, Q, H, bp);
        beta_reduce<<<1, 64, 0, stream>>>(bp, bw);
        combine_kernel<<<cBlocks, 256, 0, stream>>>(H, bw, out0);
    }

    // ===================== phase 1: product side ==================
    // attends over the UPDATED user embeddings (= out0)
    {
        zero_bp<<<1, 1024, 0, stream>>>(bp);
        proj_kernel<<<gP, 256, 0, stream>>>(product, V + MED, B_p + MD, S);
        proj_kernel<<<gP, 256, 0, stream>>>(out0, W_p + MED, nullptr, Pn);
        attn_kernel<<<gA, 256, 0, stream>>>(product, out0, product_nbrs,
                                            S, Pn, X + MD, W_q + MED, B_q + MD,
                                            Q + MD, H, bp);
        beta_reduce<<<1, 64, 0, stream>>>(bp, bw);
        combine_kernel<<<cBlocks, 256, 0, stream>>>(H, bw, out1);
    }
}

// Round 8
// 307.076 us; speedup vs baseline: 4.0284x; 1.4953x over previous
//
#include <hip/hip_runtime.h>
#include <hip/hip_bf16.h>

// Problem constants (fixed by the reference)
#define NN 8192   // nodes per side
#define ED 128    // embedding dim E
#define DD 64     // attention dim D
#define KK 32     // neighbors per node
#define MM 4      // metapaths

// -------------------------------------------------------------------------
// proj_kernel: tiled GEMM  outP[m,row,d] = sum_e emb[row,e]*W[m,e,d] (+Bias)
// Block: 256 threads -> 128-row x 64-col tile, 8x4 micro-tile per thread.
// -------------------------------------------------------------------------
__global__ __launch_bounds__(256) void proj_kernel(
    const float* __restrict__ emb,   // [NN,ED]
    const float* __restrict__ W,     // [MM,ED,DD]
    const float* __restrict__ Bias,  // [MM,DD] or nullptr
    float* __restrict__ outP)        // [MM,NN,DD]
{
    const int m   = blockIdx.y;
    const int r0  = blockIdx.x * 128;
    const int tid = threadIdx.x;

    __shared__ float A_sh[128][65];
    __shared__ float W_sh[64][64];

    const int tc = tid & 15;
    const int tr = tid >> 4;
    const int d0 = tc * 4;
    const int rb = tr * 8;

    float acc[8][4];
    #pragma unroll
    for (int i = 0; i < 8; ++i)
        #pragma unroll
        for (int c = 0; c < 4; ++c) acc[i][c] = 0.0f;

    for (int kb = 0; kb < 2; ++kb) {
        if (kb) __syncthreads();
        {
            const float4* g = (const float4*)emb;
            #pragma unroll
            for (int it = 0; it < 8; ++it) {
                const int idx = tid + it * 256;
                const int r   = idx >> 4;
                const int c4  = idx & 15;
                const float4 v = g[(size_t)(r0 + r) * (ED / 4) + kb * 16 + c4];
                float* dst = &A_sh[r][c4 * 4];
                dst[0] = v.x; dst[1] = v.y; dst[2] = v.z; dst[3] = v.w;
            }
        }
        {
            const float4* g = (const float4*)(W + ((size_t)m * ED + kb * 64) * DD);
            float4* d4 = (float4*)&W_sh[0][0];
            #pragma unroll
            for (int it = 0; it < 4; ++it)
                d4[tid + it * 256] = g[tid + it * 256];
        }
        __syncthreads();

        #pragma unroll 2
        for (int e = 0; e < 64; ++e) {
            const float4 wv = *(const float4*)&W_sh[e][d0];
            #pragma unroll
            for (int i = 0; i < 8; ++i) {
                const float a = A_sh[rb + i][e];
                acc[i][0] = fmaf(a, wv.x, acc[i][0]);
                acc[i][1] = fmaf(a, wv.y, acc[i][1]);
                acc[i][2] = fmaf(a, wv.z, acc[i][2]);
                acc[i][3] = fmaf(a, wv.w, acc[i][3]);
            }
        }
    }

    float4 bv = make_float4(0.0f, 0.0f, 0.0f, 0.0f);
    if (Bias) bv = *(const float4*)&Bias[m * DD + d0];
    #pragma unroll
    for (int i = 0; i < 8; ++i) {
        const int row = r0 + rb + i;
        float4 o;
        o.x = acc[i][0] + bv.x; o.y = acc[i][1] + bv.y;
        o.z = acc[i][2] + bv.z; o.w = acc[i][3] + bv.w;
        *(float4*)&outP[((size_t)m * NN + row) * DD + d0] = o;
    }
}

// -------------------------------------------------------------------------
// attn_kernel v2: 4 waves/block, one (m,j) per wave, ZERO LDS, no barriers.
// Scores: lane = (kg = lane>>4, d-quad = lane&15); per iteration 4 k's are
// processed (one per 16-lane row) with float4 Pn loads and a 4-step
// intra-row reduce (DPP-cheap offsets 1/2/4/8). Softmax in registers with
// 2 cross-row shuffles. H aggregation via float2. grid: (NN/4, MM).
// -------------------------------------------------------------------------
__global__ __launch_bounds__(256) void attn_kernel(
    const float* __restrict__ src,    // [NN,ED]
    const float* __restrict__ other,  // [NN,ED]
    const int*   __restrict__ nbrs,   // [MM,NN,KK]
    const float* __restrict__ S,      // [MM,NN,DD]
    const float* __restrict__ Pn,     // [MM,NN,DD]
    const float* __restrict__ Xv,     // [MM,DD]
    float* __restrict__ Hout)         // [MM,NN,ED]
{
    const int m    = blockIdx.y;
    const int tid  = threadIdx.x;
    const int w    = tid >> 6;
    const int lane = tid & 63;
    const int j    = blockIdx.x * 4 + w;

    const int kg = lane >> 4;        // which k within each quad (0..3)
    const int d0 = (lane & 15) * 4;  // d quad

    // lane l (l<32) holds neighbor id for k = l
    int idxreg = 0;
    if (lane < KK) idxreg = nbrs[((size_t)m * NN + j) * KK + lane];

    const float4 S4 = *(const float4*)(S + ((size_t)m * NN + j) * DD + d0);
    const float4 X4 = *(const float4*)(Xv + (size_t)m * DD + d0);

    float e_arr[8];  // row kg handles k = i*4 + kg
    #pragma unroll
    for (int i = 0; i < 8; ++i) {
        const int jk = __shfl(idxreg, i * 4 + kg, 64);
        const float4 P4 = *(const float4*)(Pn + ((size_t)m * NN + jk) * DD + d0);
        float p = tanhf(S4.x + P4.x) * X4.x;
        p = fmaf(tanhf(S4.y + P4.y), X4.y, p);
        p = fmaf(tanhf(S4.z + P4.z), X4.z, p);
        p = fmaf(tanhf(S4.w + P4.w), X4.w, p);
        p += __shfl_xor(p, 1, 64);
        p += __shfl_xor(p, 2, 64);
        p += __shfl_xor(p, 4, 64);
        p += __shfl_xor(p, 8, 64);
        e_arr[i] = p;                // identical across the 16 lanes of row kg
    }

    // softmax over the 32 k with the reference's full-axis baseline
    const float baseline = (m == 0) ? -1e-9f : (1.0f / (float)NN);
    float mx = e_arr[0];
    #pragma unroll
    for (int i = 1; i < 8; ++i) mx = fmaxf(mx, e_arr[i]);
    mx = fmaxf(mx, __shfl_xor(mx, 16, 64));
    mx = fmaxf(mx, __shfl_xor(mx, 32, 64));
    mx = fmaxf(mx, baseline);
    float sum = 0.0f;
    #pragma unroll
    for (int i = 0; i < 8; ++i) { e_arr[i] = expf(e_arr[i] - mx); sum += e_arr[i]; }
    sum += __shfl_xor(sum, 16, 64);
    sum += __shfl_xor(sum, 32, 64);
    const float inv_denom = 1.0f / (sum + (float)(NN - KK) * expf(baseline - mx));
    #pragma unroll
    for (int i = 0; i < 8; ++i) e_arr[i] *= inv_denom;   // A for k = i*4+kg

    // H aggregation: lane covers elements {2*lane, 2*lane+1}
    float2 h = ((const float2*)(src + (size_t)j * ED))[lane];
    #pragma unroll
    for (int k = 0; k < KK; ++k) {
        const float a  = __shfl(e_arr[k >> 2], (k & 3) * 16, 64);
        const int   jk = __shfl(idxreg, k, 64);
        const float2 o = ((const float2*)(other + (size_t)jk * ED))[lane];
        h.x = fmaf(a, o.x, h.x);
        h.y = fmaf(a, o.y, h.y);
    }
    ((float2*)(Hout + ((size_t)m * NN + j) * ED))[lane] = h;
}

// -------------------------------------------------------------------------
// sem_kernel: beta partials as a tiled GEMM over Hout.
// bp[slot,m] += sum_{j in tile} tanh(H[m,j,:] @ Wq[m] + Bq[m]) . Qv[m]
// Same tile/micro-tile as proj_kernel; epilogue does tanh+dot+block reduce.
// grid: (NN/128, MM), block 256.
// -------------------------------------------------------------------------
__global__ __launch_bounds__(256) void sem_kernel(
    const float* __restrict__ H,     // [MM,NN,ED]
    const float* __restrict__ Wq,    // [MM,ED,DD]
    const float* __restrict__ Bq,    // [MM,DD]
    const float* __restrict__ Qv,    // [MM,DD]
    float* __restrict__ bp)          // [256,MM]
{
    const int m   = blockIdx.y;
    const int r0  = blockIdx.x * 128;
    const int tid = threadIdx.x;

    __shared__ float A_sh[128][65];
    __shared__ float W_sh[64][64];
    __shared__ float red_sh[4];

    const int tc = tid & 15;
    const int tr = tid >> 4;
    const int d0 = tc * 4;
    const int rb = tr * 8;

    const float* emb = H + (size_t)m * NN * ED;

    float acc[8][4];
    #pragma unroll
    for (int i = 0; i < 8; ++i)
        #pragma unroll
        for (int c = 0; c < 4; ++c) acc[i][c] = 0.0f;

    for (int kb = 0; kb < 2; ++kb) {
        if (kb) __syncthreads();
        {
            const float4* g = (const float4*)emb;
            #pragma unroll
            for (int it = 0; it < 8; ++it) {
                const int idx = tid + it * 256;
                const int r   = idx >> 4;
                const int c4  = idx & 15;
                const float4 v = g[(size_t)(r0 + r) * (ED / 4) + kb * 16 + c4];
                float* dst = &A_sh[r][c4 * 4];
                dst[0] = v.x; dst[1] = v.y; dst[2] = v.z; dst[3] = v.w;
            }
        }
        {
            const float4* g = (const float4*)(Wq + ((size_t)m * ED + kb * 64) * DD);
            float4* d4 = (float4*)&W_sh[0][0];
            #pragma unroll
            for (int it = 0; it < 4; ++it)
                d4[tid + it * 256] = g[tid + it * 256];
        }
        __syncthreads();

        #pragma unroll 2
        for (int e = 0; e < 64; ++e) {
            const float4 wv = *(const float4*)&W_sh[e][d0];
            #pragma unroll
            for (int i = 0; i < 8; ++i) {
                const float a = A_sh[rb + i][e];
                acc[i][0] = fmaf(a, wv.x, acc[i][0]);
                acc[i][1] = fmaf(a, wv.y, acc[i][1]);
                acc[i][2] = fmaf(a, wv.z, acc[i][2]);
                acc[i][3] = fmaf(a, wv.w, acc[i][3]);
            }
        }
    }

    // epilogue: tanh + dot with Qv, then block reduction
    const float4 bq4 = *(const float4*)(Bq + (size_t)m * DD + d0);
    const float4 qv4 = *(const float4*)(Qv + (size_t)m * DD + d0);
    float part = 0.0f;
    #pragma unroll
    for (int i = 0; i < 8; ++i) {
        part = fmaf(tanhf(acc[i][0] + bq4.x), qv4.x, part);
        part = fmaf(tanhf(acc[i][1] + bq4.y), qv4.y, part);
        part = fmaf(tanhf(acc[i][2] + bq4.z), qv4.z, part);
        part = fmaf(tanhf(acc[i][3] + bq4.w), qv4.w, part);
    }
    #pragma unroll
    for (int off = 32; off; off >>= 1) part += __shfl_xor(part, off, 64);
    if ((tid & 63) == 0) red_sh[tid >> 6] = part;
    __syncthreads();
    if (tid == 0)
        atomicAdd(&bp[(blockIdx.x & 255) * MM + m],
                  (red_sh[0] + red_sh[1]) + (red_sh[2] + red_sh[3]));
}

// -------------------------------------------------------------------------
// beta_reduce: fold 256 slots -> beta_raw[m]/NN -> softmax -> bw[4]. 1 wave.
// -------------------------------------------------------------------------
__global__ void beta_reduce(const float* __restrict__ bp, float* __restrict__ bw)
{
    const int lane = threadIdx.x;     // 0..63
    const int m = lane & 3, g = lane >> 2;
    float s = 0.0f;
    for (int i = 0; i < 16; ++i)
        s += bp[(g * 16 + i) * MM + m];
    #pragma unroll
    for (int off = 4; off < 64; off <<= 1) s += __shfl_xor(s, off, 64);
    const float v = s * (1.0f / (float)NN);
    float mx = v;
    mx = fmaxf(mx, __shfl_xor(mx, 1, 64));
    mx = fmaxf(mx, __shfl_xor(mx, 2, 64));
    const float e = expf(v - mx);
    float es = e;
    es += __shfl_xor(es, 1, 64);
    es += __shfl_xor(es, 2, 64);
    if (lane < MM) bw[lane] = e / es;
}

// -------------------------------------------------------------------------
// combine: out = sum_m bw[m] * H[m]   (float4 over 1M elements)
// -------------------------------------------------------------------------
__global__ __launch_bounds__(256) void combine_kernel(
    const float* __restrict__ Hin,    // [MM,NN,ED]
    const float* __restrict__ bw,     // [4] softmaxed
    float* __restrict__ outp)         // [NN,ED]
{
    const int i = blockIdx.x * 256 + threadIdx.x;   // float4 index
    const float b0 = bw[0], b1 = bw[1], b2 = bw[2], b3 = bw[3];
    const size_t st = (size_t)NN * ED / 4;
    const float4* h = (const float4*)Hin;
    const float4 x0 = h[i], x1 = h[st + i], x2 = h[2 * st + i], x3 = h[3 * st + i];
    float4 r;
    r.x = b0 * x0.x + b1 * x1.x + b2 * x2.x + b3 * x3.x;
    r.y = b0 * x0.y + b1 * x1.y + b2 * x2.y + b3 * x3.y;
    r.z = b0 * x0.z + b1 * x1.z + b2 * x2.z + b3 * x3.z;
    r.w = b0 * x0.w + b1 * x1.w + b2 * x2.w + b3 * x3.w;
    ((float4*)outp)[i] = r;
}

__global__ void zero_bp(float* p) { p[threadIdx.x] = 0.0f; }  // <<<1,1024>>>

// -------------------------------------------------------------------------
extern "C" void kernel_launch(void* const* d_in, const int* in_sizes, int n_in,
                              void* d_out, int out_size, void* d_ws, size_t ws_size,
                              hipStream_t stream)
{
    // dict order: user, product, V, X, W_p, B_p, W_q, B_q, Q, user_nbrs, product_nbrs
    const float* user    = (const float*)d_in[0];
    const float* product = (const float*)d_in[1];
    const float* V   = (const float*)d_in[2];
    const float* X   = (const float*)d_in[3];
    const float* W_p = (const float*)d_in[4];
    const float* B_p = (const float*)d_in[5];
    const float* W_q = (const float*)d_in[6];
    const float* B_q = (const float*)d_in[7];
    const float* Q   = (const float*)d_in[8];
    const int* user_nbrs    = (const int*)d_in[9];
    const int* product_nbrs = (const int*)d_in[10];

    float* out  = (float*)d_out;            // [2,NN,ED] f32
    float* out0 = out;                      // user_out (phase-1 input too)
    float* out1 = out + (size_t)NN * ED;    // product_out

    // workspace (f32)
    float* ws = (float*)d_ws;
    float* bp = ws;                               // 256*MM = 1024
    float* bw = bp + 1024;                        // 16 (pad)
    float* S  = bw + 16;                          // MM*NN*DD
    float* Pn = S  + (size_t)MM * NN * DD;        // MM*NN*DD
    float* H  = Pn + (size_t)MM * NN * DD;        // MM*NN*ED

    const size_t MED = (size_t)MM * ED * DD;
    const size_t MD  = (size_t)MM * DD;

    const dim3 gP(NN / 128, MM);
    const dim3 gA(NN / 4, MM);
    const int cBlocks = (NN * ED / 4) / 256;

    // ===================== phase 0: user side =====================
    {
        zero_bp<<<1, 1024, 0, stream>>>(bp);
        proj_kernel<<<gP, 256, 0, stream>>>(user, V, B_p, S);
        proj_kernel<<<gP, 256, 0, stream>>>(product, W_p, nullptr, Pn);
        attn_kernel<<<gA, 256, 0, stream>>>(user, product, user_nbrs,
                                            S, Pn, X, H);
        sem_kernel<<<gP, 256, 0, stream>>>(H, W_q, B_q, Q, bp);
        beta_reduce<<<1, 64, 0, stream>>>(bp, bw);
        combine_kernel<<<cBlocks, 256, 0, stream>>>(H, bw, out0);
    }

    // ===================== phase 1: product side ==================
    // attends over the UPDATED user embeddings (= out0)
    {
        zero_bp<<<1, 1024, 0, stream>>>(bp);
        proj_kernel<<<gP, 256, 0, stream>>>(product, V + MED, B_p + MD, S);
        proj_kernel<<<gP, 256, 0, stream>>>(out0, W_p + MED, nullptr, Pn);
        attn_kernel<<<gA, 256, 0, stream>>>(product, out0, product_nbrs,
                                            S, Pn, X + MD, H);
        sem_kernel<<<gP, 256, 0, stream>>>(H, W_q + MED, B_q + MD, Q + MD, bp);
        beta_reduce<<<1, 64, 0, stream>>>(bp, bw);
        combine_kernel<<<cBlocks, 256, 0, stream>>>(H, bw, out1);
    }
}

// Round 9
// 268.778 us; speedup vs baseline: 4.6024x; 1.1425x over previous
//
#include <hip/hip_runtime.h>
#include <hip/hip_bf16.h>

// Problem constants (fixed by the reference)
#define NN 8192   // nodes per side
#define ED 128    // embedding dim E
#define DD 64     // attention dim D
#define KK 32     // neighbors per node
#define MM 4      // metapaths

// Fast tanh: tanh(x) = 1 - 2/(exp(2x)+1).
// __expf -> v_mul + v_exp_f32; rcp -> v_rcp_f32. ~6 VALU inst, no branches.
// Saturates correctly: x>>0 -> exp=inf -> rcp=0 -> 1; x<<0 -> exp=0 -> -1.
__device__ __forceinline__ float ftanh(float x)
{
    const float e = __expf(2.0f * x);
    return fmaf(-2.0f, __builtin_amdgcn_rcpf(e + 1.0f), 1.0f);
}

// -------------------------------------------------------------------------
// proj_kernel: tiled GEMM  outP[m,row,d] = sum_e emb[row,e]*W[m,e,d] (+Bias)
// Block: 256 threads -> 128-row x 64-col tile, 8x4 micro-tile per thread.
// -------------------------------------------------------------------------
__global__ __launch_bounds__(256) void proj_kernel(
    const float* __restrict__ emb,   // [NN,ED]
    const float* __restrict__ W,     // [MM,ED,DD]
    const float* __restrict__ Bias,  // [MM,DD] or nullptr
    float* __restrict__ outP)        // [MM,NN,DD]
{
    const int m   = blockIdx.y;
    const int r0  = blockIdx.x * 128;
    const int tid = threadIdx.x;

    __shared__ float A_sh[128][65];
    __shared__ float W_sh[64][64];

    const int tc = tid & 15;
    const int tr = tid >> 4;
    const int d0 = tc * 4;
    const int rb = tr * 8;

    float acc[8][4];
    #pragma unroll
    for (int i = 0; i < 8; ++i)
        #pragma unroll
        for (int c = 0; c < 4; ++c) acc[i][c] = 0.0f;

    for (int kb = 0; kb < 2; ++kb) {
        if (kb) __syncthreads();
        {
            const float4* g = (const float4*)emb;
            #pragma unroll
            for (int it = 0; it < 8; ++it) {
                const int idx = tid + it * 256;
                const int r   = idx >> 4;
                const int c4  = idx & 15;
                const float4 v = g[(size_t)(r0 + r) * (ED / 4) + kb * 16 + c4];
                float* dst = &A_sh[r][c4 * 4];
                dst[0] = v.x; dst[1] = v.y; dst[2] = v.z; dst[3] = v.w;
            }
        }
        {
            const float4* g = (const float4*)(W + ((size_t)m * ED + kb * 64) * DD);
            float4* d4 = (float4*)&W_sh[0][0];
            #pragma unroll
            for (int it = 0; it < 4; ++it)
                d4[tid + it * 256] = g[tid + it * 256];
        }
        __syncthreads();

        #pragma unroll 2
        for (int e = 0; e < 64; ++e) {
            const float4 wv = *(const float4*)&W_sh[e][d0];
            #pragma unroll
            for (int i = 0; i < 8; ++i) {
                const float a = A_sh[rb + i][e];
                acc[i][0] = fmaf(a, wv.x, acc[i][0]);
                acc[i][1] = fmaf(a, wv.y, acc[i][1]);
                acc[i][2] = fmaf(a, wv.z, acc[i][2]);
                acc[i][3] = fmaf(a, wv.w, acc[i][3]);
            }
        }
    }

    float4 bv = make_float4(0.0f, 0.0f, 0.0f, 0.0f);
    if (Bias) bv = *(const float4*)&Bias[m * DD + d0];
    #pragma unroll
    for (int i = 0; i < 8; ++i) {
        const int row = r0 + rb + i;
        float4 o;
        o.x = acc[i][0] + bv.x; o.y = acc[i][1] + bv.y;
        o.z = acc[i][2] + bv.z; o.w = acc[i][3] + bv.w;
        *(float4*)&outP[((size_t)m * NN + row) * DD + d0] = o;
    }
}

// -------------------------------------------------------------------------
// attn_kernel: 4 waves/block, one (m,j) per wave, zero LDS, no barriers.
// Scores: lane = (kg = lane>>4, d-quad = lane&15); fast tanh; 4-step
// intra-row reduce; register softmax. H aggregation via float2.
// grid: (NN/4, MM), block 256.
// -------------------------------------------------------------------------
__global__ __launch_bounds__(256) void attn_kernel(
    const float* __restrict__ src,    // [NN,ED]
    const float* __restrict__ other,  // [NN,ED]
    const int*   __restrict__ nbrs,   // [MM,NN,KK]
    const float* __restrict__ S,      // [MM,NN,DD]
    const float* __restrict__ Pn,     // [MM,NN,DD]
    const float* __restrict__ Xv,     // [MM,DD]
    float* __restrict__ Hout)         // [MM,NN,ED]
{
    const int m    = blockIdx.y;
    const int tid  = threadIdx.x;
    const int w    = tid >> 6;
    const int lane = tid & 63;
    const int j    = blockIdx.x * 4 + w;

    const int kg = lane >> 4;        // which k within each quad (0..3)
    const int d0 = (lane & 15) * 4;  // d quad

    // lane l (l<32) holds neighbor id for k = l
    int idxreg = 0;
    if (lane < KK) idxreg = nbrs[((size_t)m * NN + j) * KK + lane];

    const float4 S4 = *(const float4*)(S + ((size_t)m * NN + j) * DD + d0);
    const float4 X4 = *(const float4*)(Xv + (size_t)m * DD + d0);

    float e_arr[8];  // row kg handles k = i*4 + kg
    #pragma unroll
    for (int i = 0; i < 8; ++i) {
        const int jk = __shfl(idxreg, i * 4 + kg, 64);
        const float4 P4 = *(const float4*)(Pn + ((size_t)m * NN + jk) * DD + d0);
        float p = ftanh(S4.x + P4.x) * X4.x;
        p = fmaf(ftanh(S4.y + P4.y), X4.y, p);
        p = fmaf(ftanh(S4.z + P4.z), X4.z, p);
        p = fmaf(ftanh(S4.w + P4.w), X4.w, p);
        p += __shfl_xor(p, 1, 64);
        p += __shfl_xor(p, 2, 64);
        p += __shfl_xor(p, 4, 64);
        p += __shfl_xor(p, 8, 64);
        e_arr[i] = p;                // identical across the 16 lanes of row kg
    }

    // softmax over the 32 k with the reference's full-axis baseline
    const float baseline = (m == 0) ? -1e-9f : (1.0f / (float)NN);
    float mx = e_arr[0];
    #pragma unroll
    for (int i = 1; i < 8; ++i) mx = fmaxf(mx, e_arr[i]);
    mx = fmaxf(mx, __shfl_xor(mx, 16, 64));
    mx = fmaxf(mx, __shfl_xor(mx, 32, 64));
    mx = fmaxf(mx, baseline);
    float sum = 0.0f;
    #pragma unroll
    for (int i = 0; i < 8; ++i) { e_arr[i] = __expf(e_arr[i] - mx); sum += e_arr[i]; }
    sum += __shfl_xor(sum, 16, 64);
    sum += __shfl_xor(sum, 32, 64);
    const float inv_denom =
        __builtin_amdgcn_rcpf(sum + (float)(NN - KK) * __expf(baseline - mx));
    #pragma unroll
    for (int i = 0; i < 8; ++i) e_arr[i] *= inv_denom;   // A for k = i*4+kg

    // H aggregation: lane covers elements {2*lane, 2*lane+1}
    float2 h = ((const float2*)(src + (size_t)j * ED))[lane];
    #pragma unroll
    for (int k = 0; k < KK; ++k) {
        const float a  = __shfl(e_arr[k >> 2], (k & 3) * 16, 64);
        const int   jk = __shfl(idxreg, k, 64);
        const float2 o = ((const float2*)(other + (size_t)jk * ED))[lane];
        h.x = fmaf(a, o.x, h.x);
        h.y = fmaf(a, o.y, h.y);
    }
    ((float2*)(Hout + ((size_t)m * NN + j) * ED))[lane] = h;
}

// -------------------------------------------------------------------------
// sem_kernel: beta partials as a tiled GEMM over Hout.
// bp[slot,m] += sum_{j in tile} tanh(H[m,j,:] @ Wq[m] + Bq[m]) . Qv[m]
// grid: (NN/128, MM), block 256.
// -------------------------------------------------------------------------
__global__ __launch_bounds__(256) void sem_kernel(
    const float* __restrict__ H,     // [MM,NN,ED]
    const float* __restrict__ Wq,    // [MM,ED,DD]
    const float* __restrict__ Bq,    // [MM,DD]
    const float* __restrict__ Qv,    // [MM,DD]
    float* __restrict__ bp)          // [256,MM]
{
    const int m   = blockIdx.y;
    const int r0  = blockIdx.x * 128;
    const int tid = threadIdx.x;

    __shared__ float A_sh[128][65];
    __shared__ float W_sh[64][64];
    __shared__ float red_sh[4];

    const int tc = tid & 15;
    const int tr = tid >> 4;
    const int d0 = tc * 4;
    const int rb = tr * 8;

    const float* emb = H + (size_t)m * NN * ED;

    float acc[8][4];
    #pragma unroll
    for (int i = 0; i < 8; ++i)
        #pragma unroll
        for (int c = 0; c < 4; ++c) acc[i][c] = 0.0f;

    for (int kb = 0; kb < 2; ++kb) {
        if (kb) __syncthreads();
        {
            const float4* g = (const float4*)emb;
            #pragma unroll
            for (int it = 0; it < 8; ++it) {
                const int idx = tid + it * 256;
                const int r   = idx >> 4;
                const int c4  = idx & 15;
                const float4 v = g[(size_t)(r0 + r) * (ED / 4) + kb * 16 + c4];
                float* dst = &A_sh[r][c4 * 4];
                dst[0] = v.x; dst[1] = v.y; dst[2] = v.z; dst[3] = v.w;
            }
        }
        {
            const float4* g = (const float4*)(Wq + ((size_t)m * ED + kb * 64) * DD);
            float4* d4 = (float4*)&W_sh[0][0];
            #pragma unroll
            for (int it = 0; it < 4; ++it)
                d4[tid + it * 256] = g[tid + it * 256];
        }
        __syncthreads();

        #pragma unroll 2
        for (int e = 0; e < 64; ++e) {
            const float4 wv = *(const float4*)&W_sh[e][d0];
            #pragma unroll
            for (int i = 0; i < 8; ++i) {
                const float a = A_sh[rb + i][e];
                acc[i][0] = fmaf(a, wv.x, acc[i][0]);
                acc[i][1] = fmaf(a, wv.y, acc[i][1]);
                acc[i][2] = fmaf(a, wv.z, acc[i][2]);
                acc[i][3] = fmaf(a, wv.w, acc[i][3]);
            }
        }
    }

    // epilogue: tanh + dot with Qv, then block reduction
    const float4 bq4 = *(const float4*)(Bq + (size_t)m * DD + d0);
    const float4 qv4 = *(const float4*)(Qv + (size_t)m * DD + d0);
    float part = 0.0f;
    #pragma unroll
    for (int i = 0; i < 8; ++i) {
        part = fmaf(ftanh(acc[i][0] + bq4.x), qv4.x, part);
        part = fmaf(ftanh(acc[i][1] + bq4.y), qv4.y, part);
        part = fmaf(ftanh(acc[i][2] + bq4.z), qv4.z, part);
        part = fmaf(ftanh(acc[i][3] + bq4.w), qv4.w, part);
    }
    #pragma unroll
    for (int off = 32; off; off >>= 1) part += __shfl_xor(part, off, 64);
    if ((tid & 63) == 0) red_sh[tid >> 6] = part;
    __syncthreads();
    if (tid == 0)
        atomicAdd(&bp[(blockIdx.x & 255) * MM + m],
                  (red_sh[0] + red_sh[1]) + (red_sh[2] + red_sh[3]));
}

// -------------------------------------------------------------------------
// beta_reduce: fold 256 slots -> beta_raw[m]/NN -> softmax -> bw[4]. 1 wave.
// -------------------------------------------------------------------------
__global__ void beta_reduce(const float* __restrict__ bp, float* __restrict__ bw)
{
    const int lane = threadIdx.x;     // 0..63
    const int m = lane & 3, g = lane >> 2;
    float s = 0.0f;
    for (int i = 0; i < 16; ++i)
        s += bp[(g * 16 + i) * MM + m];
    #pragma unroll
    for (int off = 4; off < 64; off <<= 1) s += __shfl_xor(s, off, 64);
    const float v = s * (1.0f / (float)NN);
    float mx = v;
    mx = fmaxf(mx, __shfl_xor(mx, 1, 64));
    mx = fmaxf(mx, __shfl_xor(mx, 2, 64));
    const float e = expf(v - mx);
    float es = e;
    es += __shfl_xor(es, 1, 64);
    es += __shfl_xor(es, 2, 64);
    if (lane < MM) bw[lane] = e / es;
}

// -------------------------------------------------------------------------
// combine: out = sum_m bw[m] * H[m]   (float4 over 1M elements)
// -------------------------------------------------------------------------
__global__ __launch_bounds__(256) void combine_kernel(
    const float* __restrict__ Hin,    // [MM,NN,ED]
    const float* __restrict__ bw,     // [4] softmaxed
    float* __restrict__ outp)         // [NN,ED]
{
    const int i = blockIdx.x * 256 + threadIdx.x;   // float4 index
    const float b0 = bw[0], b1 = bw[1], b2 = bw[2], b3 = bw[3];
    const size_t st = (size_t)NN * ED / 4;
    const float4* h = (const float4*)Hin;
    const float4 x0 = h[i], x1 = h[st + i], x2 = h[2 * st + i], x3 = h[3 * st + i];
    float4 r;
    r.x = b0 * x0.x + b1 * x1.x + b2 * x2.x + b3 * x3.x;
    r.y = b0 * x0.y + b1 * x1.y + b2 * x2.y + b3 * x3.y;
    r.z = b0 * x0.z + b1 * x1.z + b2 * x2.z + b3 * x3.z;
    r.w = b0 * x0.w + b1 * x1.w + b2 * x2.w + b3 * x3.w;
    ((float4*)outp)[i] = r;
}

__global__ void zero_bp(float* p) { p[threadIdx.x] = 0.0f; }  // <<<1,1024>>>

// -------------------------------------------------------------------------
extern "C" void kernel_launch(void* const* d_in, const int* in_sizes, int n_in,
                              void* d_out, int out_size, void* d_ws, size_t ws_size,
                              hipStream_t stream)
{
    // dict order: user, product, V, X, W_p, B_p, W_q, B_q, Q, user_nbrs, product_nbrs
    const float* user    = (const float*)d_in[0];
    const float* product = (const float*)d_in[1];
    const float* V   = (const float*)d_in[2];
    const float* X   = (const float*)d_in[3];
    const float* W_p = (const float*)d_in[4];
    const float* B_p = (const float*)d_in[5];
    const float* W_q = (const float*)d_in[6];
    const float* B_q = (const float*)d_in[7];
    const float* Q   = (const float*)d_in[8];
    const int* user_nbrs    = (const int*)d_in[9];
    const int* product_nbrs = (const int*)d_in[10];

    float* out  = (float*)d_out;            // [2,NN,ED] f32
    float* out0 = out;                      // user_out (phase-1 input too)
    float* out1 = out + (size_t)NN * ED;    // product_out

    // workspace (f32)
    float* ws = (float*)d_ws;
    float* bp = ws;                               // 256*MM = 1024
    float* bw = bp + 1024;                        // 16 (pad)
    float* S  = bw + 16;                          // MM*NN*DD
    float* Pn = S  + (size_t)MM * NN * DD;        // MM*NN*DD
    float* H  = Pn + (size_t)MM * NN * DD;        // MM*NN*ED

    const size_t MED = (size_t)MM * ED * DD;
    const size_t MD  = (size_t)MM * DD;

    const dim3 gP(NN / 128, MM);
    const dim3 gA(NN / 4, MM);
    const int cBlocks = (NN * ED / 4) / 256;

    // ===================== phase 0: user side =====================
    {
        zero_bp<<<1, 1024, 0, stream>>>(bp);
        proj_kernel<<<gP, 256, 0, stream>>>(user, V, B_p, S);
        proj_kernel<<<gP, 256, 0, stream>>>(product, W_p, nullptr, Pn);
        attn_kernel<<<gA, 256, 0, stream>>>(user, product, user_nbrs,
                                            S, Pn, X, H);
        sem_kernel<<<gP, 256, 0, stream>>>(H, W_q, B_q, Q, bp);
        beta_reduce<<<1, 64, 0, stream>>>(bp, bw);
        combine_kernel<<<cBlocks, 256, 0, stream>>>(H, bw, out0);
    }

    // ===================== phase 1: product side ==================
    // attends over the UPDATED user embeddings (= out0)
    {
        zero_bp<<<1, 1024, 0, stream>>>(bp);
        proj_kernel<<<gP, 256, 0, stream>>>(product, V + MED, B_p + MD, S);
        proj_kernel<<<gP, 256, 0, stream>>>(out0, W_p + MED, nullptr, Pn);
        attn_kernel<<<gA, 256, 0, stream>>>(product, out0, product_nbrs,
                                            S, Pn, X + MD, H);
        sem_kernel<<<gP, 256, 0, stream>>>(H, W_q + MED, B_q + MD, Q + MD, bp);
        beta_reduce<<<1, 64, 0, stream>>>(bp, bw);
        combine_kernel<<<cBlocks, 256, 0, stream>>>(H, bw, out1);
    }
}

// Round 10
// 230.875 us; speedup vs baseline: 5.3579x; 1.1642x over previous
//
#include <hip/hip_runtime.h>
#include <hip/hip_bf16.h>

// Problem constants (fixed by the reference)
#define NN 8192   // nodes per side
#define ED 128    // embedding dim E
#define DD 64     // attention dim D
#define KK 32     // neighbors per node
#define MM 4      // metapaths

typedef __attribute__((ext_vector_type(8))) short short8;   // 8 bf16 (4 VGPRs)
typedef __attribute__((ext_vector_type(4))) float f32x4;    // MFMA acc

// Fast tanh: tanh(x) = 1 - 2/(exp(2x)+1). ~6 VALU inst, saturates correctly.
__device__ __forceinline__ float ftanh(float x)
{
    const float e = __expf(2.0f * x);
    return fmaf(-2.0f, __builtin_amdgcn_rcpf(e + 1.0f), 1.0f);
}

__device__ __forceinline__ unsigned short f2bf(float x)
{
    __hip_bfloat16 b = __float2bfloat16(x);
    return *reinterpret_cast<unsigned short*>(&b);
}
__device__ __forceinline__ float bflo(unsigned int u)  // low bf16 -> f32
{
    return __uint_as_float(u << 16);
}
__device__ __forceinline__ float bfhi(unsigned int u)  // high bf16 -> f32
{
    return __uint_as_float(u & 0xFFFF0000u);
}

// -------------------------------------------------------------------------
// convert_kernel: f32 [n] -> bf16 [n], 4 elems/thread
// -------------------------------------------------------------------------
__global__ __launch_bounds__(256) void convert_kernel(
    const float* __restrict__ in, unsigned short* __restrict__ out, int n4)
{
    const int i = blockIdx.x * 256 + threadIdx.x;
    if (i >= n4) return;
    const float4 v = ((const float4*)in)[i];
    uint2 o;
    o.x = (unsigned int)f2bf(v.x) | ((unsigned int)f2bf(v.y) << 16);
    o.y = (unsigned int)f2bf(v.z) | ((unsigned int)f2bf(v.w) << 16);
    ((uint2*)out)[i] = o;
}

// -------------------------------------------------------------------------
// transpose_kernel: W f32 [S,ED,DD] -> Wt bf16 [S,DD,ED]  (S = 2*MM slices)
// -------------------------------------------------------------------------
__global__ __launch_bounds__(256) void transpose_kernel(
    const float* __restrict__ in, unsigned short* __restrict__ out, int n)
{
    const int gid = blockIdx.x * 256 + threadIdx.x;
    if (gid >= n) return;
    const int s   = gid >> 13;          // ED*DD = 8192
    const int rem = gid & 8191;
    const int e   = rem >> 6;
    const int d   = rem & 63;
    out[((size_t)s * DD + d) * ED + e] = f2bf(in[gid]);
}

// -------------------------------------------------------------------------
// proj_mfma: outP[m,row,d] = sum_e embB[row,e]*Wt[m,d,e] (+Bias)
// MFMA 16x16x32 bf16. Block 256 = 4 waves; wave handles 16 rows x 64 cols.
// grid: (NN/64, MM). Writes f32 (outF) and/or bf16 (outB).
// A frag: A[lane&15][quad*8+j]; B frag: B[quad*8+j][lane&15];
// C/D:    col=lane&15, row=quad*4+reg   [verified layout, m89/m91]
// -------------------------------------------------------------------------
__global__ __launch_bounds__(256) void proj_mfma(
    const unsigned short* __restrict__ embB,  // [NN,ED] bf16
    const unsigned short* __restrict__ WtB,   // [MM,DD,ED] bf16 (d-major)
    const float* __restrict__ Bias,           // [MM,DD] or nullptr
    float* __restrict__ outF,                 // [MM,NN,DD] or nullptr
    unsigned short* __restrict__ outB)        // [MM,NN,DD] or nullptr
{
    const int m    = blockIdx.y;
    const int tid  = threadIdx.x;
    const int wave = tid >> 6;
    const int lane = tid & 63;
    const int nrow = lane & 15;
    const int quad = lane >> 4;
    const int r0   = blockIdx.x * 64 + wave * 16;

    const short8* A8 = (const short8*)(embB + (size_t)(r0 + nrow) * ED);
    const short8* B8 = (const short8*)(WtB + (size_t)m * DD * ED);

    f32x4 acc0 = {0.f, 0.f, 0.f, 0.f};
    f32x4 acc1 = {0.f, 0.f, 0.f, 0.f};
    f32x4 acc2 = {0.f, 0.f, 0.f, 0.f};
    f32x4 acc3 = {0.f, 0.f, 0.f, 0.f};

    #pragma unroll
    for (int kq = 0; kq < 4; ++kq) {
        const short8 a = A8[kq * 4 + quad];
        const short8 b0 = B8[(0 * 16 + nrow) * 16 + kq * 4 + quad];
        const short8 b1 = B8[(1 * 16 + nrow) * 16 + kq * 4 + quad];
        const short8 b2 = B8[(2 * 16 + nrow) * 16 + kq * 4 + quad];
        const short8 b3 = B8[(3 * 16 + nrow) * 16 + kq * 4 + quad];
        acc0 = __builtin_amdgcn_mfma_f32_16x16x32_bf16(a, b0, acc0, 0, 0, 0);
        acc1 = __builtin_amdgcn_mfma_f32_16x16x32_bf16(a, b1, acc1, 0, 0, 0);
        acc2 = __builtin_amdgcn_mfma_f32_16x16x32_bf16(a, b2, acc2, 0, 0, 0);
        acc3 = __builtin_amdgcn_mfma_f32_16x16x32_bf16(a, b3, acc3, 0, 0, 0);
    }

    f32x4 accs[4] = {acc0, acc1, acc2, acc3};
    #pragma unroll
    for (int t = 0; t < 4; ++t) {
        const int d = t * 16 + nrow;
        const float bv = Bias ? Bias[m * DD + d] : 0.0f;
        #pragma unroll
        for (int reg = 0; reg < 4; ++reg) {
            const int r = r0 + quad * 4 + reg;
            const float v = accs[t][reg] + bv;
            const size_t off = ((size_t)m * NN + r) * DD + d;
            if (outF) outF[off] = v;
            if (outB) outB[off] = f2bf(v);
        }
    }
}

// -------------------------------------------------------------------------
// attn_kernel: 4 waves/block, one (m,j) per wave, zero LDS.
// bf16 gathers (Pn, other), f32 S/src, bf16 H output.
// grid: (NN/4, MM), block 256.
// -------------------------------------------------------------------------
__global__ __launch_bounds__(256) void attn_kernel(
    const float* __restrict__ src,             // [NN,ED] f32
    const unsigned short* __restrict__ otherB, // [NN,ED] bf16
    const int*   __restrict__ nbrs,            // [MM,NN,KK]
    const float* __restrict__ S,               // [MM,NN,DD] f32
    const unsigned short* __restrict__ PnB,    // [MM,NN,DD] bf16
    const float* __restrict__ Xv,              // [MM,DD] f32
    unsigned short* __restrict__ HoutB)        // [MM,NN,ED] bf16
{
    const int m    = blockIdx.y;
    const int tid  = threadIdx.x;
    const int w    = tid >> 6;
    const int lane = tid & 63;
    const int j    = blockIdx.x * 4 + w;

    const int kg = lane >> 4;        // which k within each quad (0..3)
    const int dq = lane & 15;        // d quad index (d0 = 4*dq)

    int idxreg = 0;
    if (lane < KK) idxreg = nbrs[((size_t)m * NN + j) * KK + lane];

    const float4 S4 = *(const float4*)(S + ((size_t)m * NN + j) * DD + dq * 4);
    const float4 X4 = *(const float4*)(Xv + (size_t)m * DD + dq * 4);

    float e_arr[8];  // row kg handles k = i*4 + kg
    #pragma unroll
    for (int i = 0; i < 8; ++i) {
        const int jk = __shfl(idxreg, i * 4 + kg, 64);
        const uint2 pv = ((const uint2*)(PnB + ((size_t)m * NN + jk) * DD))[dq];
        float p = ftanh(S4.x + bflo(pv.x)) * X4.x;
        p = fmaf(ftanh(S4.y + bfhi(pv.x)), X4.y, p);
        p = fmaf(ftanh(S4.z + bflo(pv.y)), X4.z, p);
        p = fmaf(ftanh(S4.w + bfhi(pv.y)), X4.w, p);
        p += __shfl_xor(p, 1, 64);
        p += __shfl_xor(p, 2, 64);
        p += __shfl_xor(p, 4, 64);
        p += __shfl_xor(p, 8, 64);
        e_arr[i] = p;
    }

    // softmax over the 32 k with the reference's full-axis baseline
    const float baseline = (m == 0) ? -1e-9f : (1.0f / (float)NN);
    float mx = e_arr[0];
    #pragma unroll
    for (int i = 1; i < 8; ++i) mx = fmaxf(mx, e_arr[i]);
    mx = fmaxf(mx, __shfl_xor(mx, 16, 64));
    mx = fmaxf(mx, __shfl_xor(mx, 32, 64));
    mx = fmaxf(mx, baseline);
    float sum = 0.0f;
    #pragma unroll
    for (int i = 0; i < 8; ++i) { e_arr[i] = __expf(e_arr[i] - mx); sum += e_arr[i]; }
    sum += __shfl_xor(sum, 16, 64);
    sum += __shfl_xor(sum, 32, 64);
    const float inv_denom =
        __builtin_amdgcn_rcpf(sum + (float)(NN - KK) * __expf(baseline - mx));
    #pragma unroll
    for (int i = 0; i < 8; ++i) e_arr[i] *= inv_denom;   // A for k = i*4+kg

    // H aggregation: lane covers elements {2*lane, 2*lane+1}
    float2 h = ((const float2*)(src + (size_t)j * ED))[lane];
    #pragma unroll
    for (int k = 0; k < KK; ++k) {
        const float a  = __shfl(e_arr[k >> 2], (k & 3) * 16, 64);
        const int   jk = __shfl(idxreg, k, 64);
        const unsigned int ov = ((const unsigned int*)(otherB + (size_t)jk * ED))[lane];
        h.x = fmaf(a, bflo(ov), h.x);
        h.y = fmaf(a, bfhi(ov), h.y);
    }
    const unsigned int hu =
        (unsigned int)f2bf(h.x) | ((unsigned int)f2bf(h.y) << 16);
    ((unsigned int*)(HoutB + ((size_t)m * NN + j) * ED))[lane] = hu;
}

// -------------------------------------------------------------------------
// sem_mfma: beta partials. sem[j,d] = tanh((H@Wq)[j,d]+Bq[d]); partial =
// sum_{j,d} sem*Qv[d]. Same MFMA structure as proj_mfma; wave-sum epilogue.
// grid: (NN/64, MM), block 256.
// -------------------------------------------------------------------------
__global__ __launch_bounds__(256) void sem_mfma(
    const unsigned short* __restrict__ HB,    // [MM,NN,ED] bf16
    const unsigned short* __restrict__ WqT,   // [MM,DD,ED] bf16
    const float* __restrict__ Bq,             // [MM,DD]
    const float* __restrict__ Qv,             // [MM,DD]
    float* __restrict__ bp)                   // [256,MM]
{
    const int m    = blockIdx.y;
    const int tid  = threadIdx.x;
    const int wave = tid >> 6;
    const int lane = tid & 63;
    const int nrow = lane & 15;
    const int quad = lane >> 4;
    const int r0   = blockIdx.x * 64 + wave * 16;

    __shared__ float red_sh[4];

    const short8* A8 = (const short8*)(HB + ((size_t)m * NN + r0 + nrow) * ED);
    const short8* B8 = (const short8*)(WqT + (size_t)m * DD * ED);

    f32x4 acc0 = {0.f, 0.f, 0.f, 0.f};
    f32x4 acc1 = {0.f, 0.f, 0.f, 0.f};
    f32x4 acc2 = {0.f, 0.f, 0.f, 0.f};
    f32x4 acc3 = {0.f, 0.f, 0.f, 0.f};

    #pragma unroll
    for (int kq = 0; kq < 4; ++kq) {
        const short8 a = A8[kq * 4 + quad];
        const short8 b0 = B8[(0 * 16 + nrow) * 16 + kq * 4 + quad];
        const short8 b1 = B8[(1 * 16 + nrow) * 16 + kq * 4 + quad];
        const short8 b2 = B8[(2 * 16 + nrow) * 16 + kq * 4 + quad];
        const short8 b3 = B8[(3 * 16 + nrow) * 16 + kq * 4 + quad];
        acc0 = __builtin_amdgcn_mfma_f32_16x16x32_bf16(a, b0, acc0, 0, 0, 0);
        acc1 = __builtin_amdgcn_mfma_f32_16x16x32_bf16(a, b1, acc1, 0, 0, 0);
        acc2 = __builtin_amdgcn_mfma_f32_16x16x32_bf16(a, b2, acc2, 0, 0, 0);
        acc3 = __builtin_amdgcn_mfma_f32_16x16x32_bf16(a, b3, acc3, 0, 0, 0);
    }

    f32x4 accs[4] = {acc0, acc1, acc2, acc3};
    float part = 0.0f;
    #pragma unroll
    for (int t = 0; t < 4; ++t) {
        const int d = t * 16 + nrow;
        const float bq = Bq[m * DD + d];
        const float qv = Qv[m * DD + d];
        #pragma unroll
        for (int reg = 0; reg < 4; ++reg)
            part = fmaf(ftanh(accs[t][reg] + bq), qv, part);
    }
    #pragma unroll
    for (int off = 32; off; off >>= 1) part += __shfl_xor(part, off, 64);
    if (lane == 0) red_sh[wave] = part;
    __syncthreads();
    if (tid == 0)
        atomicAdd(&bp[(blockIdx.x & 255) * MM + m],
                  (red_sh[0] + red_sh[1]) + (red_sh[2] + red_sh[3]));
}

// -------------------------------------------------------------------------
// beta_reduce: fold 256 slots -> beta_raw[m]/NN -> softmax -> bw[4]. 1 wave.
// -------------------------------------------------------------------------
__global__ void beta_reduce(const float* __restrict__ bp, float* __restrict__ bw)
{
    const int lane = threadIdx.x;     // 0..63
    const int m = lane & 3, g = lane >> 2;
    float s = 0.0f;
    for (int i = 0; i < 16; ++i)
        s += bp[(g * 16 + i) * MM + m];
    #pragma unroll
    for (int off = 4; off < 64; off <<= 1) s += __shfl_xor(s, off, 64);
    const float v = s * (1.0f / (float)NN);
    float mx = v;
    mx = fmaxf(mx, __shfl_xor(mx, 1, 64));
    mx = fmaxf(mx, __shfl_xor(mx, 2, 64));
    const float e = expf(v - mx);
    float es = e;
    es += __shfl_xor(es, 1, 64);
    es += __shfl_xor(es, 2, 64);
    if (lane < MM) bw[lane] = e / es;
}

// -------------------------------------------------------------------------
// combine: out = sum_m bw[m]*H[m] from bf16 H; f32 out (+bf16 copy for
// phase-1 reuse). 4 elems/thread.
// -------------------------------------------------------------------------
__global__ __launch_bounds__(256) void combine_kernel(
    const unsigned short* __restrict__ HB,  // [MM,NN,ED] bf16
    const float* __restrict__ bw,           // [4] softmaxed
    float* __restrict__ outp,               // [NN,ED] f32
    unsigned short* __restrict__ outB)      // [NN,ED] bf16 or nullptr
{
    const int i = blockIdx.x * 256 + threadIdx.x;   // uint2 (4-elem) index
    const size_t st = (size_t)NN * ED / 4;
    const uint2* h = (const uint2*)HB;
    float r0 = 0.f, r1 = 0.f, r2 = 0.f, r3 = 0.f;
    #pragma unroll
    for (int s = 0; s < MM; ++s) {
        const float b = bw[s];
        const uint2 v = h[s * st + i];
        r0 = fmaf(b, bflo(v.x), r0);
        r1 = fmaf(b, bfhi(v.x), r1);
        r2 = fmaf(b, bflo(v.y), r2);
        r3 = fmaf(b, bfhi(v.y), r3);
    }
    float4 o; o.x = r0; o.y = r1; o.z = r2; o.w = r3;
    ((float4*)outp)[i] = o;
    if (outB) {
        uint2 ob;
        ob.x = (unsigned int)f2bf(r0) | ((unsigned int)f2bf(r1) << 16);
        ob.y = (unsigned int)f2bf(r2) | ((unsigned int)f2bf(r3) << 16);
        ((uint2*)outB)[i] = ob;
    }
}

__global__ void zero_bp(float* p) { p[threadIdx.x] = 0.0f; }  // <<<1,1024>>>

// -------------------------------------------------------------------------
extern "C" void kernel_launch(void* const* d_in, const int* in_sizes, int n_in,
                              void* d_out, int out_size, void* d_ws, size_t ws_size,
                              hipStream_t stream)
{
    // dict order: user, product, V, X, W_p, B_p, W_q, B_q, Q, user_nbrs, product_nbrs
    const float* user    = (const float*)d_in[0];
    const float* product = (const float*)d_in[1];
    const float* V   = (const float*)d_in[2];
    const float* X   = (const float*)d_in[3];
    const float* W_p = (const float*)d_in[4];
    const float* B_p = (const float*)d_in[5];
    const float* W_q = (const float*)d_in[6];
    const float* B_q = (const float*)d_in[7];
    const float* Q   = (const float*)d_in[8];
    const int* user_nbrs    = (const int*)d_in[9];
    const int* product_nbrs = (const int*)d_in[10];

    float* out  = (float*)d_out;            // [2,NN,ED] f32
    float* out0 = out;
    float* out1 = out + (size_t)NN * ED;

    // workspace layout
    float* ws = (float*)d_ws;
    float* bp = ws;                               // 1024
    float* bw = bp + 1024;                        // 16
    float* S  = bw + 16;                          // MM*NN*DD f32
    unsigned short* us = (unsigned short*)(S + (size_t)MM * NN * DD);
    unsigned short* PnB      = us;                             // MM*NN*DD
    unsigned short* HB       = PnB + (size_t)MM * NN * DD;     // MM*NN*ED
    unsigned short* userB    = HB + (size_t)MM * NN * ED;      // NN*ED
    unsigned short* productB = userB + (size_t)NN * ED;        // NN*ED
    unsigned short* oB       = productB + (size_t)NN * ED;     // NN*ED
    unsigned short* VT       = oB + (size_t)NN * ED;           // 2*MM*DD*ED
    unsigned short* PT       = VT + (size_t)2 * MM * DD * ED;
    unsigned short* QT       = PT + (size_t)2 * MM * DD * ED;

    const size_t MED = (size_t)MM * ED * DD;   // per-phase slice (weights)
    const size_t MD  = (size_t)MM * DD;

    const dim3 gM(NN / 64, MM);                // MFMA GEMM grids
    const dim3 gA(NN / 4, MM);
    const int cBlocks = (NN * ED / 4) / 256;
    const int wN = 2 * MM * ED * DD;           // whole weight tensor

    // ---------------- prep: bf16 conversions & weight transposes ----------
    convert_kernel<<<cBlocks, 256, 0, stream>>>(user, userB, NN * ED / 4);
    convert_kernel<<<cBlocks, 256, 0, stream>>>(product, productB, NN * ED / 4);
    transpose_kernel<<<wN / 256, 256, 0, stream>>>(V, VT, wN);
    transpose_kernel<<<wN / 256, 256, 0, stream>>>(W_p, PT, wN);
    transpose_kernel<<<wN / 256, 256, 0, stream>>>(W_q, QT, wN);

    // ===================== phase 0: user side =====================
    {
        zero_bp<<<1, 1024, 0, stream>>>(bp);
        proj_mfma<<<gM, 256, 0, stream>>>(userB, VT, B_p, S, nullptr);
        proj_mfma<<<gM, 256, 0, stream>>>(productB, PT, nullptr, nullptr, PnB);
        attn_kernel<<<gA, 256, 0, stream>>>(user, productB, user_nbrs,
                                            S, PnB, X, HB);
        sem_mfma<<<gM, 256, 0, stream>>>(HB, QT, B_q, Q, bp);
        beta_reduce<<<1, 64, 0, stream>>>(bp, bw);
        combine_kernel<<<cBlocks, 256, 0, stream>>>(HB, bw, out0, oB);
    }

    // ===================== phase 1: product side ==================
    // attends over the UPDATED user embeddings (= out0 / oB)
    {
        zero_bp<<<1, 1024, 0, stream>>>(bp);
        proj_mfma<<<gM, 256, 0, stream>>>(productB, VT + MED, B_p + MD, S, nullptr);
        proj_mfma<<<gM, 256, 0, stream>>>(oB, PT + MED, nullptr, nullptr, PnB);
        attn_kernel<<<gA, 256, 0, stream>>>(product, oB, product_nbrs,
                                            S, PnB, X + MD, HB);
        sem_mfma<<<gM, 256, 0, stream>>>(HB, QT + MED, B_q + MD, Q + MD, bp);
        beta_reduce<<<1, 64, 0, stream>>>(bp, bw);
        combine_kernel<<<cBlocks, 256, 0, stream>>>(HB, bw, out1, nullptr);
    }
}

// Round 11
// 210.276 us; speedup vs baseline: 5.8828x; 1.0980x over previous
//
#include <hip/hip_runtime.h>
#include <hip/hip_bf16.h>

// Problem constants (fixed by the reference)
#define NN 8192   // nodes per side
#define ED 128    // embedding dim E
#define DD 64     // attention dim D
#define KK 32     // neighbors per node
#define MM 4      // metapaths

typedef __attribute__((ext_vector_type(8))) short short8;   // 8 bf16 (4 VGPRs)
typedef __attribute__((ext_vector_type(4))) float f32x4;    // MFMA acc

// Fast tanh: tanh(x) = 1 - 2/(exp(2x)+1). Saturates correctly at +/-1.
__device__ __forceinline__ float ftanh(float x)
{
    const float e = __expf(2.0f * x);
    return fmaf(-2.0f, __builtin_amdgcn_rcpf(e + 1.0f), 1.0f);
}

__device__ __forceinline__ unsigned short f2bf(float x)
{
    __hip_bfloat16 b = __float2bfloat16(x);
    return *reinterpret_cast<unsigned short*>(&b);
}
__device__ __forceinline__ float bflo(unsigned int u) { return __uint_as_float(u << 16); }
__device__ __forceinline__ float bfhi(unsigned int u) { return __uint_as_float(u & 0xFFFF0000u); }
__device__ __forceinline__ float readlane_f(float v, int lane)
{
    return __uint_as_float(__builtin_amdgcn_readlane(__float_as_uint(v), lane));
}

// -------------------------------------------------------------------------
// convert2: f32 -> bf16 for user (y=0) and product (y=1). 4 elems/thread.
// grid: (NN*ED/4/256, 2)
// -------------------------------------------------------------------------
__global__ __launch_bounds__(256) void convert2_kernel(
    const float* __restrict__ inA, unsigned short* __restrict__ outA,
    const float* __restrict__ inB, unsigned short* __restrict__ outB)
{
    const float* in = blockIdx.y ? inB : inA;
    unsigned short* out = blockIdx.y ? outB : outA;
    const int i = blockIdx.x * 256 + threadIdx.x;
    const float4 v = ((const float4*)in)[i];
    uint2 o;
    o.x = (unsigned int)f2bf(v.x) | ((unsigned int)f2bf(v.y) << 16);
    o.y = (unsigned int)f2bf(v.z) | ((unsigned int)f2bf(v.w) << 16);
    ((uint2*)out)[i] = o;
}

// -------------------------------------------------------------------------
// transpose3: W f32 [S,ED,DD] -> Wt bf16 [S,DD,ED] for V (y=0), W_p (y=1),
// W_q (y=2). S = 2*MM slices. grid: (2*MM*ED*DD/256, 3)
// -------------------------------------------------------------------------
__global__ __launch_bounds__(256) void transpose3_kernel(
    const float* __restrict__ inV, unsigned short* __restrict__ outV,
    const float* __restrict__ inP, unsigned short* __restrict__ outP,
    const float* __restrict__ inQ, unsigned short* __restrict__ outQ)
{
    const float* in = (blockIdx.y == 0) ? inV : (blockIdx.y == 1) ? inP : inQ;
    unsigned short* out = (blockIdx.y == 0) ? outV : (blockIdx.y == 1) ? outP : outQ;
    const int gid = blockIdx.x * 256 + threadIdx.x;
    const int s   = gid >> 13;          // ED*DD = 8192
    const int rem = gid & 8191;
    const int e   = rem >> 6;
    const int d   = rem & 63;
    out[((size_t)s * DD + d) * ED + e] = f2bf(in[gid]);
}

// -------------------------------------------------------------------------
// proj2_mfma: both per-phase projections in one launch (blockIdx.z):
//   z=0: S  = emb0 @ Wt0 + Bias0 -> f32 outF0
//   z=1: Pn = emb1 @ Wt1         -> bf16 outB1
// MFMA 16x16x32 bf16; wave = 16 rows x 64 cols. grid: (NN/64, MM, 2).
// A frag: A[lane&15][quad*8+j]; B frag: B[quad*8+j][lane&15];
// C/D: col=lane&15, row=quad*4+reg   [verified layout, m89/m91]
// -------------------------------------------------------------------------
__global__ __launch_bounds__(256) void proj2_mfma(
    const unsigned short* __restrict__ emb0,  // [NN,ED] bf16
    const unsigned short* __restrict__ Wt0,   // [MM,DD,ED] bf16
    const float* __restrict__ Bias0,          // [MM,DD]
    float* __restrict__ outF0,                // [MM,NN,DD] f32
    const unsigned short* __restrict__ emb1,  // [NN,ED] bf16
    const unsigned short* __restrict__ Wt1,   // [MM,DD,ED] bf16
    unsigned short* __restrict__ outB1)       // [MM,NN,DD] bf16
{
    const int z    = blockIdx.z;
    const int m    = blockIdx.y;
    const int tid  = threadIdx.x;
    const int wave = tid >> 6;
    const int lane = tid & 63;
    const int nrow = lane & 15;
    const int quad = lane >> 4;
    const int r0   = blockIdx.x * 64 + wave * 16;

    const unsigned short* embB = z ? emb1 : emb0;
    const unsigned short* WtB  = z ? Wt1 : Wt0;

    const short8* A8 = (const short8*)(embB + (size_t)(r0 + nrow) * ED);
    const short8* B8 = (const short8*)(WtB + (size_t)m * DD * ED);

    f32x4 acc0 = {0.f, 0.f, 0.f, 0.f};
    f32x4 acc1 = {0.f, 0.f, 0.f, 0.f};
    f32x4 acc2 = {0.f, 0.f, 0.f, 0.f};
    f32x4 acc3 = {0.f, 0.f, 0.f, 0.f};

    #pragma unroll
    for (int kq = 0; kq < 4; ++kq) {
        const short8 a = A8[kq * 4 + quad];
        const short8 b0 = B8[(0 * 16 + nrow) * 16 + kq * 4 + quad];
        const short8 b1 = B8[(1 * 16 + nrow) * 16 + kq * 4 + quad];
        const short8 b2 = B8[(2 * 16 + nrow) * 16 + kq * 4 + quad];
        const short8 b3 = B8[(3 * 16 + nrow) * 16 + kq * 4 + quad];
        acc0 = __builtin_amdgcn_mfma_f32_16x16x32_bf16(a, b0, acc0, 0, 0, 0);
        acc1 = __builtin_amdgcn_mfma_f32_16x16x32_bf16(a, b1, acc1, 0, 0, 0);
        acc2 = __builtin_amdgcn_mfma_f32_16x16x32_bf16(a, b2, acc2, 0, 0, 0);
        acc3 = __builtin_amdgcn_mfma_f32_16x16x32_bf16(a, b3, acc3, 0, 0, 0);
    }

    f32x4 accs[4] = {acc0, acc1, acc2, acc3};
    if (z == 0) {
        #pragma unroll
        for (int t = 0; t < 4; ++t) {
            const int d = t * 16 + nrow;
            const float bv = Bias0[m * DD + d];
            #pragma unroll
            for (int reg = 0; reg < 4; ++reg) {
                const int r = r0 + quad * 4 + reg;
                outF0[((size_t)m * NN + r) * DD + d] = accs[t][reg] + bv;
            }
        }
    } else {
        #pragma unroll
        for (int t = 0; t < 4; ++t) {
            const int d = t * 16 + nrow;
            #pragma unroll
            for (int reg = 0; reg < 4; ++reg) {
                const int r = r0 + quad * 4 + reg;
                outB1[((size_t)m * NN + r) * DD + d] = f2bf(accs[t][reg]);
            }
        }
    }
}

// -------------------------------------------------------------------------
// attn_kernel: 4 waves/block, one (m,j) per wave, zero LDS.
// bf16 gathers (Pn, other); H-agg uses readlane scalarization (SGPR
// broadcast + saddr loads). grid: (NN/4, MM), block 256.
// -------------------------------------------------------------------------
__global__ __launch_bounds__(256) void attn_kernel(
    const float* __restrict__ src,             // [NN,ED] f32
    const unsigned short* __restrict__ otherB, // [NN,ED] bf16
    const int*   __restrict__ nbrs,            // [MM,NN,KK]
    const float* __restrict__ S,               // [MM,NN,DD] f32
    const unsigned short* __restrict__ PnB,    // [MM,NN,DD] bf16
    const float* __restrict__ Xv,              // [MM,DD] f32
    unsigned short* __restrict__ HoutB)        // [MM,NN,ED] bf16
{
    const int m    = blockIdx.y;
    const int tid  = threadIdx.x;
    const int w    = tid >> 6;
    const int lane = tid & 63;
    const int j    = blockIdx.x * 4 + w;

    const int kg = lane >> 4;        // which k within each quad (0..3)
    const int dq = lane & 15;        // d quad index (d0 = 4*dq)

    int idxreg = 0;
    if (lane < KK) idxreg = nbrs[((size_t)m * NN + j) * KK + lane];

    const float4 S4 = *(const float4*)(S + ((size_t)m * NN + j) * DD + dq * 4);
    const float4 X4 = *(const float4*)(Xv + (size_t)m * DD + dq * 4);

    float e_arr[8];  // row kg handles k = i*4 + kg
    #pragma unroll
    for (int i = 0; i < 8; ++i) {
        const int jk = __shfl(idxreg, i * 4 + kg, 64);
        const uint2 pv = ((const uint2*)(PnB + ((size_t)m * NN + jk) * DD))[dq];
        float p = ftanh(S4.x + bflo(pv.x)) * X4.x;
        p = fmaf(ftanh(S4.y + bfhi(pv.x)), X4.y, p);
        p = fmaf(ftanh(S4.z + bflo(pv.y)), X4.z, p);
        p = fmaf(ftanh(S4.w + bfhi(pv.y)), X4.w, p);
        p += __shfl_xor(p, 1, 64);
        p += __shfl_xor(p, 2, 64);
        p += __shfl_xor(p, 4, 64);
        p += __shfl_xor(p, 8, 64);
        e_arr[i] = p;
    }

    // softmax over the 32 k with the reference's full-axis baseline
    const float baseline = (m == 0) ? -1e-9f : (1.0f / (float)NN);
    float mx = e_arr[0];
    #pragma unroll
    for (int i = 1; i < 8; ++i) mx = fmaxf(mx, e_arr[i]);
    mx = fmaxf(mx, __shfl_xor(mx, 16, 64));
    mx = fmaxf(mx, __shfl_xor(mx, 32, 64));
    mx = fmaxf(mx, baseline);
    float sum = 0.0f;
    #pragma unroll
    for (int i = 0; i < 8; ++i) { e_arr[i] = __expf(e_arr[i] - mx); sum += e_arr[i]; }
    sum += __shfl_xor(sum, 16, 64);
    sum += __shfl_xor(sum, 32, 64);
    const float inv_denom =
        __builtin_amdgcn_rcpf(sum + (float)(NN - KK) * __expf(baseline - mx));
    #pragma unroll
    for (int i = 0; i < 8; ++i) e_arr[i] *= inv_denom;   // A for k = i*4+kg

    // H aggregation: lane covers elements {2*lane, 2*lane+1}.
    // a and jk are wave-uniform per k -> readlane to SGPR (scalar addr + fma
    // with SGPR operand). e_arr[i] is valid in all lanes (butterfly sums);
    // lane (k&3)*16 belongs to row kg=k&3 which computed k = (k>>2)*4+kg.
    float2 h = ((const float2*)(src + (size_t)j * ED))[lane];
    #pragma unroll
    for (int k = 0; k < KK; ++k) {
        const float a  = readlane_f(e_arr[k >> 2], (k & 3) * 16);
        const int   jk = __builtin_amdgcn_readlane(idxreg, k);
        const unsigned int ov = ((const unsigned int*)(otherB + (size_t)jk * ED))[lane];
        h.x = fmaf(a, bflo(ov), h.x);
        h.y = fmaf(a, bfhi(ov), h.y);
    }
    const unsigned int hu =
        (unsigned int)f2bf(h.x) | ((unsigned int)f2bf(h.y) << 16);
    ((unsigned int*)(HoutB + ((size_t)m * NN + j) * ED))[lane] = hu;
}

// -------------------------------------------------------------------------
// sem_mfma: per-block beta partials, NO atomics (direct slot write).
// bp[m*128 + bx] = sum over the block's 64 rows of tanh(H@Wq+Bq).Qv
// grid: (NN/64, MM), block 256.
// -------------------------------------------------------------------------
__global__ __launch_bounds__(256) void sem_mfma(
    const unsigned short* __restrict__ HB,    // [MM,NN,ED] bf16
    const unsigned short* __restrict__ WqT,   // [MM,DD,ED] bf16
    const float* __restrict__ Bq,             // [MM,DD]
    const float* __restrict__ Qv,             // [MM,DD]
    float* __restrict__ bp)                   // [MM*128]
{
    const int m    = blockIdx.y;
    const int tid  = threadIdx.x;
    const int wave = tid >> 6;
    const int lane = tid & 63;
    const int nrow = lane & 15;
    const int quad = lane >> 4;
    const int r0   = blockIdx.x * 64 + wave * 16;

    __shared__ float red_sh[4];

    const short8* A8 = (const short8*)(HB + ((size_t)m * NN + r0 + nrow) * ED);
    const short8* B8 = (const short8*)(WqT + (size_t)m * DD * ED);

    f32x4 acc0 = {0.f, 0.f, 0.f, 0.f};
    f32x4 acc1 = {0.f, 0.f, 0.f, 0.f};
    f32x4 acc2 = {0.f, 0.f, 0.f, 0.f};
    f32x4 acc3 = {0.f, 0.f, 0.f, 0.f};

    #pragma unroll
    for (int kq = 0; kq < 4; ++kq) {
        const short8 a = A8[kq * 4 + quad];
        const short8 b0 = B8[(0 * 16 + nrow) * 16 + kq * 4 + quad];
        const short8 b1 = B8[(1 * 16 + nrow) * 16 + kq * 4 + quad];
        const short8 b2 = B8[(2 * 16 + nrow) * 16 + kq * 4 + quad];
        const short8 b3 = B8[(3 * 16 + nrow) * 16 + kq * 4 + quad];
        acc0 = __builtin_amdgcn_mfma_f32_16x16x32_bf16(a, b0, acc0, 0, 0, 0);
        acc1 = __builtin_amdgcn_mfma_f32_16x16x32_bf16(a, b1, acc1, 0, 0, 0);
        acc2 = __builtin_amdgcn_mfma_f32_16x16x32_bf16(a, b2, acc2, 0, 0, 0);
        acc3 = __builtin_amdgcn_mfma_f32_16x16x32_bf16(a, b3, acc3, 0, 0, 0);
    }

    f32x4 accs[4] = {acc0, acc1, acc2, acc3};
    float part = 0.0f;
    #pragma unroll
    for (int t = 0; t < 4; ++t) {
        const int d = t * 16 + nrow;
        const float bq = Bq[m * DD + d];
        const float qv = Qv[m * DD + d];
        #pragma unroll
        for (int reg = 0; reg < 4; ++reg)
            part = fmaf(ftanh(accs[t][reg] + bq), qv, part);
    }
    #pragma unroll
    for (int off = 32; off; off >>= 1) part += __shfl_xor(part, off, 64);
    if (lane == 0) red_sh[wave] = part;
    __syncthreads();
    if (tid == 0)
        bp[m * 128 + blockIdx.x] =
            (red_sh[0] + red_sh[1]) + (red_sh[2] + red_sh[3]);
}

// -------------------------------------------------------------------------
// beta_reduce: 512 slots [m*128+i] -> beta softmax -> bw[4]. 1 wave.
// Lane layout: m = lane>>4, t = lane&15; lane sums slots t, t+16, ... (8).
// -------------------------------------------------------------------------
__global__ void beta_reduce(const float* __restrict__ bp, float* __restrict__ bw)
{
    const int lane = threadIdx.x;     // 0..63
    const int m = lane >> 4, t = lane & 15;
    float s = 0.0f;
    #pragma unroll
    for (int i = 0; i < 8; ++i)
        s += bp[m * 128 + t + i * 16];
    // butterfly within the 16-lane group -> all group lanes hold the m-sum
    s += __shfl_xor(s, 1, 64);
    s += __shfl_xor(s, 2, 64);
    s += __shfl_xor(s, 4, 64);
    s += __shfl_xor(s, 8, 64);
    const float v = s * (1.0f / (float)NN);
    float mx = v;
    mx = fmaxf(mx, __shfl_xor(mx, 16, 64));
    mx = fmaxf(mx, __shfl_xor(mx, 32, 64));
    const float e = expf(v - mx);
    float es = e;
    es += __shfl_xor(es, 16, 64);
    es += __shfl_xor(es, 32, 64);
    if (t == 0) bw[m] = e / es;
}

// -------------------------------------------------------------------------
// combine: out = sum_m bw[m]*H[m] from bf16 H; f32 out (+bf16 for phase-1).
// -------------------------------------------------------------------------
__global__ __launch_bounds__(256) void combine_kernel(
    const unsigned short* __restrict__ HB,  // [MM,NN,ED] bf16
    const float* __restrict__ bw,           // [4] softmaxed
    float* __restrict__ outp,               // [NN,ED] f32
    unsigned short* __restrict__ outB)      // [NN,ED] bf16 or nullptr
{
    const int i = blockIdx.x * 256 + threadIdx.x;   // uint2 (4-elem) index
    const size_t st = (size_t)NN * ED / 4;
    const uint2* h = (const uint2*)HB;
    float r0 = 0.f, r1 = 0.f, r2 = 0.f, r3 = 0.f;
    #pragma unroll
    for (int s = 0; s < MM; ++s) {
        const float b = bw[s];
        const uint2 v = h[s * st + i];
        r0 = fmaf(b, bflo(v.x), r0);
        r1 = fmaf(b, bfhi(v.x), r1);
        r2 = fmaf(b, bflo(v.y), r2);
        r3 = fmaf(b, bfhi(v.y), r3);
    }
    float4 o; o.x = r0; o.y = r1; o.z = r2; o.w = r3;
    ((float4*)outp)[i] = o;
    if (outB) {
        uint2 ob;
        ob.x = (unsigned int)f2bf(r0) | ((unsigned int)f2bf(r1) << 16);
        ob.y = (unsigned int)f2bf(r2) | ((unsigned int)f2bf(r3) << 16);
        ((uint2*)outB)[i] = ob;
    }
}

// -------------------------------------------------------------------------
extern "C" void kernel_launch(void* const* d_in, const int* in_sizes, int n_in,
                              void* d_out, int out_size, void* d_ws, size_t ws_size,
                              hipStream_t stream)
{
    // dict order: user, product, V, X, W_p, B_p, W_q, B_q, Q, user_nbrs, product_nbrs
    const float* user    = (const float*)d_in[0];
    const float* product = (const float*)d_in[1];
    const float* V   = (const float*)d_in[2];
    const float* X   = (const float*)d_in[3];
    const float* W_p = (const float*)d_in[4];
    const float* B_p = (const float*)d_in[5];
    const float* W_q = (const float*)d_in[6];
    const float* B_q = (const float*)d_in[7];
    const float* Q   = (const float*)d_in[8];
    const int* user_nbrs    = (const int*)d_in[9];
    const int* product_nbrs = (const int*)d_in[10];

    float* out  = (float*)d_out;            // [2,NN,ED] f32
    float* out0 = out;
    float* out1 = out + (size_t)NN * ED;

    // workspace layout
    float* ws = (float*)d_ws;
    float* bp = ws;                               // 512 (pad 1024)
    float* bw = bp + 1024;                        // 16
    float* S  = bw + 16;                          // MM*NN*DD f32
    unsigned short* us = (unsigned short*)(S + (size_t)MM * NN * DD);
    unsigned short* PnB      = us;                             // MM*NN*DD
    unsigned short* HB       = PnB + (size_t)MM * NN * DD;     // MM*NN*ED
    unsigned short* userB    = HB + (size_t)MM * NN * ED;      // NN*ED
    unsigned short* productB = userB + (size_t)NN * ED;        // NN*ED
    unsigned short* oB       = productB + (size_t)NN * ED;     // NN*ED
    unsigned short* VT       = oB + (size_t)NN * ED;           // 2*MM*DD*ED
    unsigned short* PT       = VT + (size_t)2 * MM * DD * ED;
    unsigned short* QT       = PT + (size_t)2 * MM * DD * ED;

    const size_t MED = (size_t)MM * ED * DD;   // per-phase weight slice
    const size_t MD  = (size_t)MM * DD;

    const dim3 gM2(NN / 64, MM, 2);            // fused proj grid
    const dim3 gM(NN / 64, MM);                // sem grid
    const dim3 gA(NN / 4, MM);
    const int cBlocks = (NN * ED / 4) / 256;
    const int wN = 2 * MM * ED * DD;           // whole weight tensor elems

    // ---------------- prep: bf16 conversions & weight transposes ----------
    convert2_kernel<<<dim3(cBlocks, 2), 256, 0, stream>>>(user, userB,
                                                          product, productB);
    transpose3_kernel<<<dim3(wN / 256, 3), 256, 0, stream>>>(V, VT, W_p, PT,
                                                             W_q, QT);

    // ===================== phase 0: user side =====================
    {
        proj2_mfma<<<gM2, 256, 0, stream>>>(userB, VT, B_p, S,
                                            productB, PT, PnB);
        attn_kernel<<<gA, 256, 0, stream>>>(user, productB, user_nbrs,
                                            S, PnB, X, HB);
        sem_mfma<<<gM, 256, 0, stream>>>(HB, QT, B_q, Q, bp);
        beta_reduce<<<1, 64, 0, stream>>>(bp, bw);
        combine_kernel<<<cBlocks, 256, 0, stream>>>(HB, bw, out0, oB);
    }

    // ===================== phase 1: product side ==================
    // attends over the UPDATED user embeddings (= out0 / oB)
    {
        proj2_mfma<<<gM2, 256, 0, stream>>>(productB, VT + MED, B_p + MD, S,
                                            oB, PT + MED, PnB);
        attn_kernel<<<gA, 256, 0, stream>>>(product, oB, product_nbrs,
                                            S, PnB, X + MD, HB);
        sem_mfma<<<gM, 256, 0, stream>>>(HB, QT + MED, B_q + MD, Q + MD, bp);
        beta_reduce<<<1, 64, 0, stream>>>(bp, bw);
        combine_kernel<<<cBlocks, 256, 0, stream>>>(HB, bw, out1, nullptr);
    }
}